// Round 1
// baseline (3135.337 us; speedup 1.0000x reference)
//
#include <hip/hip_runtime.h>
#include <hip/hip_bf16.h>
#include <math.h>

#define H_ 100
#define W_ 152
#define HW_ 15200
#define C_ 512
#define A_ 9
#define NA_ 136800        // HW*A
#define NSORT_ 262144     // 2^18 >= NA
#define PRE_NMS_ 6000
#define NB_PAD_ 6016      // PRE_NMS padded to 64
#define NWORDS_ 94        // ceil(6000/64)
#define POST_NMS_ 300

// ---------------------------------------------------------------------------
// Kernel 1: 3x3 conv (SAME) + bias + ReLU, fp32.
// Output layout transposed: xt[p][co]  (p = h*W+w), for coalesced stage-2 reads.
// Block: 256 threads. Tile: 4 rows x 32 cols (128 pos) x 128 co.
// Thread: 4 co x 16 cols of one row.
// ---------------------------------------------------------------------------
__global__ __launch_bounds__(256) void conv3x3_relu(
    const float* __restrict__ fm, const float* __restrict__ cw,
    const float* __restrict__ cb, float* __restrict__ xt)
{
    __shared__ float in_lds[4][6][36];    // [ci_sub][row+halo][col+halo(34 used)]
    __shared__ float w_lds[36][128];      // [ci_sub*9+tap][co]

    const int tid = threadIdx.x;
    const int w0 = blockIdx.x * 32;
    const int h0 = blockIdx.y * 4;
    const int co_base = blockIdx.z * 128;
    const int co_grp = tid & 31;          // 0..31 -> co0 = 4*co_grp
    const int pos_grp = tid >> 5;         // 0..7
    const int r = pos_grp & 3;            // row within tile
    const int ch16 = (pos_grp >> 2) * 16; // col-half base

    float acc[4][16];
#pragma unroll
    for (int a = 0; a < 4; a++)
#pragma unroll
        for (int j = 0; j < 16; j++) acc[a][j] = 0.f;

    for (int ci0 = 0; ci0 < 512; ci0 += 4) {
        __syncthreads();
        // stage input 4ci x 6rows x 34cols (zero-padded at borders)
        for (int idx = tid; idx < 816; idx += 256) {
            int cc  = idx / 204;
            int rem = idx - cc * 204;
            int rr  = rem / 34;
            int cl  = rem - rr * 34;
            int hh = h0 + rr - 1;
            int ww = w0 + cl - 1;
            float v = 0.f;
            if (hh >= 0 && hh < H_ && ww >= 0 && ww < W_)
                v = fm[(size_t)(ci0 + cc) * HW_ + hh * W_ + ww];
            in_lds[cc][rr][cl] = v;
        }
        // stage weights 128co x (4ci x 9taps) via float4 (rows are 36-float aligned)
        for (int idx = tid; idx < 1152; idx += 256) {
            int co = idx & 127;
            int g  = idx >> 7;            // 0..8
            const float4 v = *(const float4*)(cw + (size_t)(co_base + co) * 4608 + ci0 * 9 + g * 4);
            w_lds[g * 4 + 0][co] = v.x;
            w_lds[g * 4 + 1][co] = v.y;
            w_lds[g * 4 + 2][co] = v.z;
            w_lds[g * 4 + 3][co] = v.w;
        }
        __syncthreads();

#pragma unroll
        for (int cc = 0; cc < 4; cc++) {
            float4 wv[9];
#pragma unroll
            for (int kk = 0; kk < 9; kk++)
                wv[kk] = *(const float4*)&w_lds[cc * 9 + kk][co_grp * 4];
#pragma unroll
            for (int dy = 0; dy < 3; dy++) {
                float win[18];
#pragma unroll
                for (int u = 0; u < 18; u++) win[u] = in_lds[cc][r + dy][ch16 + u];
#pragma unroll
                for (int dx = 0; dx < 3; dx++) {
                    float4 wk = wv[dy * 3 + dx];
#pragma unroll
                    for (int j = 0; j < 16; j++) {
                        float iv = win[j + dx];
                        acc[0][j] = fmaf(iv, wk.x, acc[0][j]);
                        acc[1][j] = fmaf(iv, wk.y, acc[1][j]);
                        acc[2][j] = fmaf(iv, wk.z, acc[2][j]);
                        acc[3][j] = fmaf(iv, wk.w, acc[3][j]);
                    }
                }
            }
        }
    }

    const int co0 = co_base + co_grp * 4;
    const float4 bias = *(const float4*)(cb + co0);
    const int hh = h0 + r;
#pragma unroll
    for (int j = 0; j < 16; j++) {
        int ww = w0 + ch16 + j;
        if (ww < W_) {
            float4 o;
            o.x = fmaxf(acc[0][j] + bias.x, 0.f);
            o.y = fmaxf(acc[1][j] + bias.y, 0.f);
            o.z = fmaxf(acc[2][j] + bias.z, 0.f);
            o.w = fmaxf(acc[3][j] + bias.w, 0.f);
            *(float4*)(xt + (size_t)(hh * W_ + ww) * 512 + co0) = o;
        }
    }
}

// ---------------------------------------------------------------------------
// Kernel 2: 1x1 convs (cls 18ch + bbox 36ch) + softmax fg + anchors + bbox
// transform + clip + min-size filter. One block = 16 positions.
// ---------------------------------------------------------------------------
__device__ const float g_bx1[9] = {-84.f,-176.f,-360.f,-56.f,-120.f,-248.f,-36.f,-80.f,-168.f};
__device__ const float g_by1[9] = {-40.f,-88.f,-184.f,-56.f,-120.f,-248.f,-80.f,-168.f,-344.f};
__device__ const float g_bx2[9] = {99.f,191.f,375.f,71.f,135.f,263.f,51.f,95.f,183.f};
__device__ const float g_by2[9] = {55.f,103.f,199.f,71.f,135.f,263.f,95.f,183.f,359.f};

__global__ __launch_bounds__(256) void rpn_head(
    const float* __restrict__ xt,
    const float* __restrict__ cls_w, const float* __restrict__ cls_b,
    const float* __restrict__ bbox_w, const float* __restrict__ bbox_b,
    const float* __restrict__ im_info,
    float* __restrict__ scores, float4* __restrict__ boxes)
{
    __shared__ float xl[16 * 512];
    __shared__ float raw[16][56];
    const int tid = threadIdx.x;
    const int p0 = blockIdx.x * 16;

    // stage x for 16 positions (contiguous 32KB)
    {
        const float4* src = (const float4*)(xt + (size_t)p0 * 512);
        float4* dst = (float4*)xl;
        for (int i = tid; i < 2048; i += 256) dst[i] = src[i];
    }
    __syncthreads();

    if (tid < 216) {
        int c  = tid % 54;
        int pg = tid / 54;               // 0..3, 4 positions each
        const float* wrow = (c < 18) ? (cls_w + (size_t)c * 512)
                                     : (bbox_w + (size_t)(c - 18) * 512);
        float b = (c < 18) ? cls_b[c] : bbox_b[c - 18];
        float a0 = b, a1 = b, a2 = b, a3 = b;
        const float* x0 = xl + (size_t)(pg * 4) * 512;
        for (int ci = 0; ci < 512; ci++) {
            float wv = wrow[ci];
            a0 = fmaf(wv, x0[ci], a0);
            a1 = fmaf(wv, x0[512 + ci], a1);
            a2 = fmaf(wv, x0[1024 + ci], a2);
            a3 = fmaf(wv, x0[1536 + ci], a3);
        }
        raw[pg * 4 + 0][c] = a0;
        raw[pg * 4 + 1][c] = a1;
        raw[pg * 4 + 2][c] = a2;
        raw[pg * 4 + 3][c] = a3;
    }
    __syncthreads();

    if (tid < 144) {
        int pos = tid / 9;
        int a   = tid % 9;
        int p = p0 + pos;
        int hh = p / 152;
        int ww = p - hh * 152;

        float s0 = raw[pos][a], s1 = raw[pos][9 + a];
        float fg = 1.f / (1.f + expf(s0 - s1));

        float dx = raw[pos][18 + 4 * a + 0];
        float dy = raw[pos][18 + 4 * a + 1];
        float dw = raw[pos][18 + 4 * a + 2];
        float dh = raw[pos][18 + 4 * a + 3];

        float sx = ww * 16.f, sy = hh * 16.f;
        float ax1 = g_bx1[a] + sx, ay1 = g_by1[a] + sy;
        float ax2 = g_bx2[a] + sx, ay2 = g_by2[a] + sy;
        float aw = ax2 - ax1 + 1.f, ah = ay2 - ay1 + 1.f;
        float axc = ax1 + 0.5f * aw, ayc = ay1 + 0.5f * ah;

        float px = dx * aw + axc, py = dy * ah + ayc;
        float pw = expf(dw) * aw, ph = expf(dh) * ah;
        float x1 = px - 0.5f * pw, y1 = py - 0.5f * ph;
        float x2 = px + 0.5f * pw, y2 = py + 0.5f * ph;

        float imh = im_info[0], imw = im_info[1], scl = im_info[2];
        x1 = fminf(fmaxf(x1, 0.f), imw - 1.f);
        y1 = fminf(fmaxf(y1, 0.f), imh - 1.f);
        x2 = fminf(fmaxf(x2, 0.f), imw - 1.f);
        y2 = fminf(fmaxf(y2, 0.f), imh - 1.f);

        float wd = x2 - x1 + 1.f, hd = y2 - y1 + 1.f;
        bool valid = (wd >= 16.f * scl) && (hd >= 16.f * scl);

        int idx = p * 9 + a;
        scores[idx] = valid ? fg : -1000000000.f;
        boxes[idx] = make_float4(x1, y1, x2, y2);
    }
}

// ---------------------------------------------------------------------------
// Top-K: exact bitonic sort (descending) of u64 keys (sortable_score, ~index)
// ---------------------------------------------------------------------------
__global__ void build_keys(const float* __restrict__ scores,
                           unsigned long long* __restrict__ keys)
{
    int i = blockIdx.x * 256 + threadIdx.x;
    if (i >= NSORT_) return;
    unsigned long long k = 0ull;
    if (i < NA_) {
        unsigned u = __float_as_uint(scores[i]);
        u = (u & 0x80000000u) ? ~u : (u | 0x80000000u);
        k = ((unsigned long long)u << 32) | (unsigned)(0xFFFFFFFFu - (unsigned)i);
    }
    keys[i] = k;
}

__device__ __forceinline__ void cex(unsigned long long* s, int i, int l, bool desc)
{
    unsigned long long a = s[i], b = s[l];
    if (desc ? (a < b) : (a > b)) { s[i] = b; s[l] = a; }
}

__global__ __launch_bounds__(256) void bitonic_local_sort(unsigned long long* __restrict__ keys)
{
    __shared__ unsigned long long s[4096];
    const int tid = threadIdx.x;
    const int base = blockIdx.x * 4096;
    for (int i = tid; i < 4096; i += 256) s[i] = keys[base + i];
    __syncthreads();
    for (int k = 2; k <= 4096; k <<= 1) {
        for (int j = k >> 1; j > 0; j >>= 1) {
#pragma unroll
            for (int m = 0; m < 8; m++) {
                int p = tid + m * 256;
                int i = ((p & ~(j - 1)) << 1) | (p & (j - 1));
                int l = i | j;
                bool desc = (((base + i) & k) == 0);
                cex(s, i, l, desc);
            }
            __syncthreads();
        }
    }
    for (int i = tid; i < 4096; i += 256) keys[base + i] = s[i];
}

__global__ void bitonic_global(unsigned long long* __restrict__ keys, int j, int k)
{
    int p = blockIdx.x * 256 + threadIdx.x;      // pair index
    int i = ((p & ~(j - 1)) << 1) | (p & (j - 1));
    int l = i | j;
    bool desc = ((i & k) == 0);
    unsigned long long a = keys[i], b = keys[l];
    if (desc ? (a < b) : (a > b)) { keys[i] = b; keys[l] = a; }
}

__global__ __launch_bounds__(256) void bitonic_local_merge(unsigned long long* __restrict__ keys, int k)
{
    __shared__ unsigned long long s[4096];
    const int tid = threadIdx.x;
    const int base = blockIdx.x * 4096;
    const bool desc = ((base & k) == 0);     // uniform for k >= 8192
    for (int i = tid; i < 4096; i += 256) s[i] = keys[base + i];
    __syncthreads();
    for (int j = 2048; j > 0; j >>= 1) {
#pragma unroll
        for (int m = 0; m < 8; m++) {
            int p = tid + m * 256;
            int i = ((p & ~(j - 1)) << 1) | (p & (j - 1));
            cex(s, i, i | j, desc);
        }
        __syncthreads();
    }
    for (int i = tid; i < 4096; i += 256) keys[base + i] = s[i];
}

// ---------------------------------------------------------------------------
// Gather top-6000 (padded to 6016) boxes/scores/areas in sorted order
// ---------------------------------------------------------------------------
__global__ void gather_top(const unsigned long long* __restrict__ keys,
                           const float* __restrict__ scores,
                           const float4* __restrict__ boxes,
                           float4* __restrict__ nb, float* __restrict__ sc,
                           float* __restrict__ area)
{
    int r = blockIdx.x * 256 + threadIdx.x;
    if (r >= NB_PAD_) return;
    if (r < PRE_NMS_) {
        unsigned long long key = keys[r];
        unsigned idx = 0xFFFFFFFFu - (unsigned)(key & 0xFFFFFFFFull);
        float4 b = boxes[idx];
        nb[r] = b;
        sc[r] = scores[idx];
        area[r] = (b.z - b.x + 1.f) * (b.w - b.y + 1.f);
    } else {
        nb[r] = make_float4(0.f, 0.f, 0.f, 0.f);
        sc[r] = -1000000000.f;
        area[r] = 1.f;
    }
}

// ---------------------------------------------------------------------------
// NMS suppression bitmatrix: mask[i][cb] bit b = (j=cb*64+b suppressed by i)
// ---------------------------------------------------------------------------
__global__ __launch_bounds__(64) void nms_mask(const float4* __restrict__ nb,
                                               const float* __restrict__ area,
                                               unsigned long long* __restrict__ mask)
{
    __shared__ float4 cbox[64];
    __shared__ float carea[64];
    const int t = threadIdx.x;
    const int cbk = blockIdx.x, rb = blockIdx.y;
    const int jBase = cbk * 64;
    cbox[t] = nb[jBase + t];
    carea[t] = area[jBase + t];
    __syncthreads();

    const int i = rb * 64 + t;
    const float4 bi = nb[i];
    const float ai = area[i];
    unsigned long long bits = 0ull;
#pragma unroll 8
    for (int b = 0; b < 64; b++) {
        int j = jBase + b;
        if (j > i) {
            float4 bj = cbox[b];
            float xx1 = fmaxf(bi.x, bj.x), yy1 = fmaxf(bi.y, bj.y);
            float xx2 = fminf(bi.z, bj.z), yy2 = fminf(bi.w, bj.w);
            float iw = fmaxf(0.f, xx2 - xx1 + 1.f);
            float ih = fmaxf(0.f, yy2 - yy1 + 1.f);
            float inter = iw * ih;
            float iou = inter / (ai + carea[b] - inter);
            if (iou > 0.7f) bits |= (1ull << b);
        }
    }
    mask[(size_t)i * NWORDS_ + cbk] = bits;
}

// ---------------------------------------------------------------------------
// Serial NMS scan: single wave, remv bitset in registers (94 words: r0 + r1)
// ---------------------------------------------------------------------------
__global__ __launch_bounds__(64) void nms_scan(const unsigned long long* __restrict__ mask,
                                               int* __restrict__ keep)
{
    const int lane = threadIdx.x;
    unsigned long long r0 = 0ull, r1 = 0ull;
    for (int j = 0; j < PRE_NMS_; j++) {
        int w = j >> 6;
        unsigned long long word = (w < 64) ? __shfl(r0, w) : __shfl(r1, w - 64);
        int sup = (int)((word >> (j & 63)) & 1ull);
        if (!sup) {
            r0 |= mask[(size_t)j * NWORDS_ + lane];
            if (lane < NWORDS_ - 64) r1 |= mask[(size_t)j * NWORDS_ + 64 + lane];
            if (lane == 0) keep[j] = 1;
        } else {
            if (lane == 0) keep[j] = 0;
        }
    }
}

// ---------------------------------------------------------------------------
// Final: top-300 of kept (then non-kept in index order to fill) -> rois
// ---------------------------------------------------------------------------
__global__ __launch_bounds__(64) void final_out(const int* __restrict__ keep,
                                                const float* __restrict__ sc,
                                                const float4* __restrict__ nb,
                                                float* __restrict__ out)
{
    __shared__ int sel[POST_NMS_];
    const int lane = threadIdx.x;
    const unsigned long long lmask = (lane == 0) ? 0ull : ((~0ull) >> (64 - lane));

    int cnt = 0;
    for (int c = 0; c < NWORDS_ && cnt < POST_NMS_; c++) {
        int j = c * 64 + lane;
        bool k = (j < PRE_NMS_) && keep[j] && (sc[j] > -5e8f);
        unsigned long long bal = __ballot(k);
        int pos = cnt + __popcll(bal & lmask);
        if (k && pos < POST_NMS_) sel[pos] = j;
        cnt += __popcll(bal);
    }
    if (cnt < POST_NMS_) {
        for (int c = 0; c < NWORDS_ && cnt < POST_NMS_; c++) {
            int j = c * 64 + lane;
            bool k = (j < PRE_NMS_) && !(keep[j] && (sc[j] > -5e8f));
            unsigned long long bal = __ballot(k);
            int pos = cnt + __popcll(bal & lmask);
            if (k && pos < POST_NMS_) sel[pos] = j;
            cnt += __popcll(bal);
        }
    }
    __syncthreads();
    for (int i = lane; i < POST_NMS_; i += 64) {
        int j = sel[i];
        float4 b = nb[j];
        out[i * 5 + 0] = 0.f;
        out[i * 5 + 1] = b.x;
        out[i * 5 + 2] = b.y;
        out[i * 5 + 3] = b.z;
        out[i * 5 + 4] = b.w;
    }
}

// ---------------------------------------------------------------------------
extern "C" void kernel_launch(void* const* d_in, const int* in_sizes, int n_in,
                              void* d_out, int out_size, void* d_ws, size_t ws_size,
                              hipStream_t stream)
{
    const float* fm      = (const float*)d_in[0];
    const float* im_info = (const float*)d_in[1];
    const float* conv_w  = (const float*)d_in[2];
    const float* conv_b  = (const float*)d_in[3];
    const float* cls_w   = (const float*)d_in[4];
    const float* cls_b   = (const float*)d_in[5];
    const float* bbox_w  = (const float*)d_in[6];
    const float* bbox_b  = (const float*)d_in[7];
    float* out = (float*)d_out;

    char* ws = (char*)d_ws;
    size_t off = 0;
    auto alloc = [&](size_t bytes) -> void* {
        void* p = ws + off;
        off = (off + bytes + 255) & ~(size_t)255;
        return p;
    };
    float* xt                 = (float*)alloc((size_t)HW_ * 512 * 4);          // 31.1 MB
    float* scores             = (float*)alloc((size_t)NA_ * 4);                // 0.55 MB
    float4* boxes             = (float4*)alloc((size_t)NA_ * 16);              // 2.2 MB
    unsigned long long* keys  = (unsigned long long*)alloc((size_t)NSORT_ * 8);// 2.1 MB
    float4* nb                = (float4*)alloc((size_t)NB_PAD_ * 16);
    float* sc                 = (float*)alloc((size_t)NB_PAD_ * 4);
    float* area               = (float*)alloc((size_t)NB_PAD_ * 4);
    unsigned long long* mask  = (unsigned long long*)alloc((size_t)NB_PAD_ * NWORDS_ * 8); // 4.5 MB
    int* keep                 = (int*)alloc((size_t)NB_PAD_ * 4);

    conv3x3_relu<<<dim3(5, 25, 4), 256, 0, stream>>>(fm, conv_w, conv_b, xt);
    rpn_head<<<dim3(950), 256, 0, stream>>>(xt, cls_w, cls_b, bbox_w, bbox_b,
                                            im_info, scores, boxes);
    build_keys<<<dim3(NSORT_ / 256), 256, 0, stream>>>(scores, keys);
    bitonic_local_sort<<<dim3(NSORT_ / 4096), 256, 0, stream>>>(keys);
    for (int k = 8192; k <= NSORT_; k <<= 1) {
        for (int j = k >> 1; j >= 4096; j >>= 1)
            bitonic_global<<<dim3(NSORT_ / 2 / 256), 256, 0, stream>>>(keys, j, k);
        bitonic_local_merge<<<dim3(NSORT_ / 4096), 256, 0, stream>>>(keys, k);
    }
    gather_top<<<dim3((NB_PAD_ + 255) / 256), 256, 0, stream>>>(keys, scores, boxes,
                                                                nb, sc, area);
    nms_mask<<<dim3(NWORDS_, NWORDS_), 64, 0, stream>>>(nb, area, mask);
    nms_scan<<<dim3(1), 64, 0, stream>>>(mask, keep);
    final_out<<<dim3(1), 64, 0, stream>>>(keep, sc, nb, out);
}

// Round 2
// 1772.006 us; speedup vs baseline: 1.7694x; 1.7694x over previous
//
#include <hip/hip_runtime.h>
#include <hip/hip_bf16.h>
#include <math.h>

#define H_ 100
#define W_ 152
#define HW_ 15200
#define C_ 512
#define A_ 9
#define NA_ 136800        // HW*A
#define NSORT_ 262144     // 2^18 >= NA
#define PRE_NMS_ 6000
#define NB_PAD_ 6016      // PRE_NMS padded to 64
#define NWORDS_ 94        // ceil(6000/64)
#define POST_NMS_ 300

// ---------------------------------------------------------------------------
// Kernel 1: 3x3 conv (SAME) + bias + ReLU, fp32.
// Output layout transposed: xt[p][co]  (p = h*W+w), for coalesced stage-2 reads.
// Block: 256 threads. Tile: 4 rows x 32 cols (128 pos) x 128 co.
// Thread: 4 co x 16 cols of one row.
// ---------------------------------------------------------------------------
__global__ __launch_bounds__(256) void conv3x3_relu(
    const float* __restrict__ fm, const float* __restrict__ cw,
    const float* __restrict__ cb, float* __restrict__ xt)
{
    __shared__ float in_lds[4][6][36];    // [ci_sub][row+halo][col+halo(34 used)]
    __shared__ float w_lds[36][128];      // [ci_sub*9+tap][co]

    const int tid = threadIdx.x;
    const int w0 = blockIdx.x * 32;
    const int h0 = blockIdx.y * 4;
    const int co_base = blockIdx.z * 128;
    const int co_grp = tid & 31;          // 0..31 -> co0 = 4*co_grp
    const int pos_grp = tid >> 5;         // 0..7
    const int r = pos_grp & 3;            // row within tile
    const int ch16 = (pos_grp >> 2) * 16; // col-half base

    float acc[4][16];
#pragma unroll
    for (int a = 0; a < 4; a++)
#pragma unroll
        for (int j = 0; j < 16; j++) acc[a][j] = 0.f;

    for (int ci0 = 0; ci0 < 512; ci0 += 4) {
        __syncthreads();
        // stage input 4ci x 6rows x 34cols (zero-padded at borders)
        for (int idx = tid; idx < 816; idx += 256) {
            int cc  = idx / 204;
            int rem = idx - cc * 204;
            int rr  = rem / 34;
            int cl  = rem - rr * 34;
            int hh = h0 + rr - 1;
            int ww = w0 + cl - 1;
            float v = 0.f;
            if (hh >= 0 && hh < H_ && ww >= 0 && ww < W_)
                v = fm[(size_t)(ci0 + cc) * HW_ + hh * W_ + ww];
            in_lds[cc][rr][cl] = v;
        }
        // stage weights 128co x (4ci x 9taps) via float4 (rows are 36-float aligned)
        for (int idx = tid; idx < 1152; idx += 256) {
            int co = idx & 127;
            int g  = idx >> 7;            // 0..8
            const float4 v = *(const float4*)(cw + (size_t)(co_base + co) * 4608 + ci0 * 9 + g * 4);
            w_lds[g * 4 + 0][co] = v.x;
            w_lds[g * 4 + 1][co] = v.y;
            w_lds[g * 4 + 2][co] = v.z;
            w_lds[g * 4 + 3][co] = v.w;
        }
        __syncthreads();

#pragma unroll
        for (int cc = 0; cc < 4; cc++) {
            float4 wv[9];
#pragma unroll
            for (int kk = 0; kk < 9; kk++)
                wv[kk] = *(const float4*)&w_lds[cc * 9 + kk][co_grp * 4];
#pragma unroll
            for (int dy = 0; dy < 3; dy++) {
                float win[18];
#pragma unroll
                for (int u = 0; u < 18; u++) win[u] = in_lds[cc][r + dy][ch16 + u];
#pragma unroll
                for (int dx = 0; dx < 3; dx++) {
                    float4 wk = wv[dy * 3 + dx];
#pragma unroll
                    for (int j = 0; j < 16; j++) {
                        float iv = win[j + dx];
                        acc[0][j] = fmaf(iv, wk.x, acc[0][j]);
                        acc[1][j] = fmaf(iv, wk.y, acc[1][j]);
                        acc[2][j] = fmaf(iv, wk.z, acc[2][j]);
                        acc[3][j] = fmaf(iv, wk.w, acc[3][j]);
                    }
                }
            }
        }
    }

    const int co0 = co_base + co_grp * 4;
    const float4 bias = *(const float4*)(cb + co0);
    const int hh = h0 + r;
#pragma unroll
    for (int j = 0; j < 16; j++) {
        int ww = w0 + ch16 + j;
        if (ww < W_) {
            float4 o;
            o.x = fmaxf(acc[0][j] + bias.x, 0.f);
            o.y = fmaxf(acc[1][j] + bias.y, 0.f);
            o.z = fmaxf(acc[2][j] + bias.z, 0.f);
            o.w = fmaxf(acc[3][j] + bias.w, 0.f);
            *(float4*)(xt + (size_t)(hh * W_ + ww) * 512 + co0) = o;
        }
    }
}

// ---------------------------------------------------------------------------
// Kernel 2: 1x1 convs (cls 18ch + bbox 36ch) + softmax fg + anchors + bbox
// transform + clip + min-size filter. One block = 16 positions.
// ---------------------------------------------------------------------------
__device__ const float g_bx1[9] = {-84.f,-176.f,-360.f,-56.f,-120.f,-248.f,-36.f,-80.f,-168.f};
__device__ const float g_by1[9] = {-40.f,-88.f,-184.f,-56.f,-120.f,-248.f,-80.f,-168.f,-344.f};
__device__ const float g_bx2[9] = {99.f,191.f,375.f,71.f,135.f,263.f,51.f,95.f,183.f};
__device__ const float g_by2[9] = {55.f,103.f,199.f,71.f,135.f,263.f,95.f,183.f,359.f};

__global__ __launch_bounds__(256) void rpn_head(
    const float* __restrict__ xt,
    const float* __restrict__ cls_w, const float* __restrict__ cls_b,
    const float* __restrict__ bbox_w, const float* __restrict__ bbox_b,
    const float* __restrict__ im_info,
    float* __restrict__ scores, float4* __restrict__ boxes)
{
    __shared__ float xl[16 * 512];
    __shared__ float raw[16][56];
    const int tid = threadIdx.x;
    const int p0 = blockIdx.x * 16;

    // stage x for 16 positions (contiguous 32KB)
    {
        const float4* src = (const float4*)(xt + (size_t)p0 * 512);
        float4* dst = (float4*)xl;
        for (int i = tid; i < 2048; i += 256) dst[i] = src[i];
    }
    __syncthreads();

    if (tid < 216) {
        int c  = tid % 54;
        int pg = tid / 54;               // 0..3, 4 positions each
        const float* wrow = (c < 18) ? (cls_w + (size_t)c * 512)
                                     : (bbox_w + (size_t)(c - 18) * 512);
        float b = (c < 18) ? cls_b[c] : bbox_b[c - 18];
        float a0 = b, a1 = b, a2 = b, a3 = b;
        const float* x0 = xl + (size_t)(pg * 4) * 512;
        for (int ci = 0; ci < 512; ci++) {
            float wv = wrow[ci];
            a0 = fmaf(wv, x0[ci], a0);
            a1 = fmaf(wv, x0[512 + ci], a1);
            a2 = fmaf(wv, x0[1024 + ci], a2);
            a3 = fmaf(wv, x0[1536 + ci], a3);
        }
        raw[pg * 4 + 0][c] = a0;
        raw[pg * 4 + 1][c] = a1;
        raw[pg * 4 + 2][c] = a2;
        raw[pg * 4 + 3][c] = a3;
    }
    __syncthreads();

    if (tid < 144) {
        int pos = tid / 9;
        int a   = tid % 9;
        int p = p0 + pos;
        int hh = p / 152;
        int ww = p - hh * 152;

        float s0 = raw[pos][a], s1 = raw[pos][9 + a];
        float fg = 1.f / (1.f + expf(s0 - s1));

        float dx = raw[pos][18 + 4 * a + 0];
        float dy = raw[pos][18 + 4 * a + 1];
        float dw = raw[pos][18 + 4 * a + 2];
        float dh = raw[pos][18 + 4 * a + 3];

        float sx = ww * 16.f, sy = hh * 16.f;
        float ax1 = g_bx1[a] + sx, ay1 = g_by1[a] + sy;
        float ax2 = g_bx2[a] + sx, ay2 = g_by2[a] + sy;
        float aw = ax2 - ax1 + 1.f, ah = ay2 - ay1 + 1.f;
        float axc = ax1 + 0.5f * aw, ayc = ay1 + 0.5f * ah;

        float px = dx * aw + axc, py = dy * ah + ayc;
        float pw = expf(dw) * aw, ph = expf(dh) * ah;
        float x1 = px - 0.5f * pw, y1 = py - 0.5f * ph;
        float x2 = px + 0.5f * pw, y2 = py + 0.5f * ph;

        float imh = im_info[0], imw = im_info[1], scl = im_info[2];
        x1 = fminf(fmaxf(x1, 0.f), imw - 1.f);
        y1 = fminf(fmaxf(y1, 0.f), imh - 1.f);
        x2 = fminf(fmaxf(x2, 0.f), imw - 1.f);
        y2 = fminf(fmaxf(y2, 0.f), imh - 1.f);

        float wd = x2 - x1 + 1.f, hd = y2 - y1 + 1.f;
        bool valid = (wd >= 16.f * scl) && (hd >= 16.f * scl);

        int idx = p * 9 + a;
        scores[idx] = valid ? fg : -1000000000.f;
        boxes[idx] = make_float4(x1, y1, x2, y2);
    }
}

// ---------------------------------------------------------------------------
// Top-K: exact bitonic sort (descending) of u64 keys (sortable_score, ~index)
// ---------------------------------------------------------------------------
__global__ void build_keys(const float* __restrict__ scores,
                           unsigned long long* __restrict__ keys)
{
    int i = blockIdx.x * 256 + threadIdx.x;
    if (i >= NSORT_) return;
    unsigned long long k = 0ull;
    if (i < NA_) {
        unsigned u = __float_as_uint(scores[i]);
        u = (u & 0x80000000u) ? ~u : (u | 0x80000000u);
        k = ((unsigned long long)u << 32) | (unsigned)(0xFFFFFFFFu - (unsigned)i);
    }
    keys[i] = k;
}

__device__ __forceinline__ void cex(unsigned long long* s, int i, int l, bool desc)
{
    unsigned long long a = s[i], b = s[l];
    if (desc ? (a < b) : (a > b)) { s[i] = b; s[l] = a; }
}

__global__ __launch_bounds__(256) void bitonic_local_sort(unsigned long long* __restrict__ keys)
{
    __shared__ unsigned long long s[4096];
    const int tid = threadIdx.x;
    const int base = blockIdx.x * 4096;
    for (int i = tid; i < 4096; i += 256) s[i] = keys[base + i];
    __syncthreads();
    for (int k = 2; k <= 4096; k <<= 1) {
        for (int j = k >> 1; j > 0; j >>= 1) {
#pragma unroll
            for (int m = 0; m < 8; m++) {
                int p = tid + m * 256;
                int i = ((p & ~(j - 1)) << 1) | (p & (j - 1));
                int l = i | j;
                bool desc = (((base + i) & k) == 0);
                cex(s, i, l, desc);
            }
            __syncthreads();
        }
    }
    for (int i = tid; i < 4096; i += 256) keys[base + i] = s[i];
}

__global__ void bitonic_global(unsigned long long* __restrict__ keys, int j, int k)
{
    int p = blockIdx.x * 256 + threadIdx.x;      // pair index
    int i = ((p & ~(j - 1)) << 1) | (p & (j - 1));
    int l = i | j;
    bool desc = ((i & k) == 0);
    unsigned long long a = keys[i], b = keys[l];
    if (desc ? (a < b) : (a > b)) { keys[i] = b; keys[l] = a; }
}

__global__ __launch_bounds__(256) void bitonic_local_merge(unsigned long long* __restrict__ keys, int k)
{
    __shared__ unsigned long long s[4096];
    const int tid = threadIdx.x;
    const int base = blockIdx.x * 4096;
    const bool desc = ((base & k) == 0);     // uniform for k >= 8192
    for (int i = tid; i < 4096; i += 256) s[i] = keys[base + i];
    __syncthreads();
    for (int j = 2048; j > 0; j >>= 1) {
#pragma unroll
        for (int m = 0; m < 8; m++) {
            int p = tid + m * 256;
            int i = ((p & ~(j - 1)) << 1) | (p & (j - 1));
            cex(s, i, i | j, desc);
        }
        __syncthreads();
    }
    for (int i = tid; i < 4096; i += 256) keys[base + i] = s[i];
}

// ---------------------------------------------------------------------------
// Gather top-6000 (padded to 6016) boxes/scores/areas in sorted order
// ---------------------------------------------------------------------------
__global__ void gather_top(const unsigned long long* __restrict__ keys,
                           const float* __restrict__ scores,
                           const float4* __restrict__ boxes,
                           float4* __restrict__ nb, float* __restrict__ sc,
                           float* __restrict__ area)
{
    int r = blockIdx.x * 256 + threadIdx.x;
    if (r >= NB_PAD_) return;
    if (r < PRE_NMS_) {
        unsigned long long key = keys[r];
        unsigned idx = 0xFFFFFFFFu - (unsigned)(key & 0xFFFFFFFFull);
        float4 b = boxes[idx];
        nb[r] = b;
        sc[r] = scores[idx];
        area[r] = (b.z - b.x + 1.f) * (b.w - b.y + 1.f);
    } else {
        nb[r] = make_float4(0.f, 0.f, 0.f, 0.f);
        sc[r] = -1000000000.f;
        area[r] = 1.f;
    }
}

// ---------------------------------------------------------------------------
// NMS suppression bitmatrix: mask[i][cb] bit b = (j=cb*64+b suppressed by i)
// Also writes the diagonal block word to diag[i] (for the scan's intra-block
// resolution) so the scan can load it coalesced.
// ---------------------------------------------------------------------------
__global__ __launch_bounds__(64) void nms_mask(const float4* __restrict__ nb,
                                               const float* __restrict__ area,
                                               unsigned long long* __restrict__ mask,
                                               unsigned long long* __restrict__ diag)
{
    __shared__ float4 cbox[64];
    __shared__ float carea[64];
    const int t = threadIdx.x;
    const int cbk = blockIdx.x, rb = blockIdx.y;
    const int jBase = cbk * 64;
    cbox[t] = nb[jBase + t];
    carea[t] = area[jBase + t];
    __syncthreads();

    const int i = rb * 64 + t;
    const float4 bi = nb[i];
    const float ai = area[i];
    unsigned long long bits = 0ull;
#pragma unroll 8
    for (int b = 0; b < 64; b++) {
        int j = jBase + b;
        if (j > i) {
            float4 bj = cbox[b];
            float xx1 = fmaxf(bi.x, bj.x), yy1 = fmaxf(bi.y, bj.y);
            float xx2 = fminf(bi.z, bj.z), yy2 = fminf(bi.w, bj.w);
            float iw = fmaxf(0.f, xx2 - xx1 + 1.f);
            float ih = fmaxf(0.f, yy2 - yy1 + 1.f);
            float inter = iw * ih;
            float iou = inter / (ai + carea[b] - inter);
            if (iou > 0.7f) bits |= (1ull << b);
        }
    }
    mask[(size_t)i * NWORDS_ + cbk] = bits;
    if (cbk == rb) diag[i] = bits;
}

// ---------------------------------------------------------------------------
// Block-serial NMS scan. One wave scans 94 blocks of 64 candidates.
//  - remv bitset distributed: lane w holds word w (r0: words 0..63, r1: 64..93)
//  - intra-block resolution: scalar ffs/readlane chain over precomputed
//    64x64 diagonal words (LDS)
//  - remv update: kept rows' mask words OR'd in, batched 8 rows/iter so the
//    ~500-cycle L2/L3 load latency is amortized 8x
// ---------------------------------------------------------------------------
__device__ __forceinline__ unsigned long long readlane_u64(unsigned long long v, int l)
{
    unsigned int lo = (unsigned int)__builtin_amdgcn_readlane((int)(unsigned int)(v & 0xffffffffull), l);
    unsigned int hi = (unsigned int)__builtin_amdgcn_readlane((int)(unsigned int)(v >> 32), l);
    return ((unsigned long long)hi << 32) | (unsigned long long)lo;
}

__global__ __launch_bounds__(256) void nms_scan(const unsigned long long* __restrict__ mask,
                                                const unsigned long long* __restrict__ diag,
                                                int* __restrict__ keep)
{
    __shared__ unsigned long long dlds[NB_PAD_];   // 48.1 KB
    const int tid = threadIdx.x;
    for (int i = tid; i < NB_PAD_; i += 256) dlds[i] = diag[i];
    __syncthreads();
    if (tid >= 64) return;

    const int lane = tid;
    unsigned long long r0 = 0ull, r1 = 0ull;

    for (int c = 0; c < NWORDS_; c++) {
        unsigned long long ext = (c < 64) ? readlane_u64(r0, c) : readlane_u64(r1, c - 64);
        unsigned long long myDiag = dlds[c * 64 + lane];

        // scalar intra-block resolution
        unsigned long long alive = ~ext;
        unsigned long long todo = alive;
        while (todo) {
            int l = (int)__builtin_ctzll(todo);
            todo &= todo - 1;
            unsigned long long d = readlane_u64(myDiag, l);
            alive &= ~d;
            todo &= ~d;
        }

        keep[c * 64 + lane] = (int)((alive >> lane) & 1ull);

        // OR kept rows into remv, 8 rows per batch (loads overlapped)
        unsigned long long kept = alive;
        while (kept) {
            unsigned long long v0[8], v1[8];
            int valid[8];
#pragma unroll
            for (int t = 0; t < 8; t++) {
                valid[t] = (kept != 0ull) ? 1 : 0;
                int bit = valid[t] ? (int)__builtin_ctzll(kept) : 0;
                if (valid[t]) kept &= kept - 1;
                const unsigned long long* row = mask + (size_t)(c * 64 + bit) * NWORDS_;
                v0[t] = row[lane];
                v1[t] = (lane < NWORDS_ - 64) ? row[64 + lane] : 0ull;
            }
#pragma unroll
            for (int t = 0; t < 8; t++) {
                if (valid[t]) { r0 |= v0[t]; r1 |= v1[t]; }
            }
        }
    }
}

// ---------------------------------------------------------------------------
// Final: top-300 of kept (then non-kept in index order to fill) -> rois
// ---------------------------------------------------------------------------
__global__ __launch_bounds__(64) void final_out(const int* __restrict__ keep,
                                                const float* __restrict__ sc,
                                                const float4* __restrict__ nb,
                                                float* __restrict__ out)
{
    __shared__ int sel[POST_NMS_];
    const int lane = threadIdx.x;
    const unsigned long long lmask = (lane == 0) ? 0ull : ((~0ull) >> (64 - lane));

    int cnt = 0;
    for (int c = 0; c < NWORDS_ && cnt < POST_NMS_; c++) {
        int j = c * 64 + lane;
        bool k = (j < PRE_NMS_) && keep[j] && (sc[j] > -5e8f);
        unsigned long long bal = __ballot(k);
        int pos = cnt + __popcll(bal & lmask);
        if (k && pos < POST_NMS_) sel[pos] = j;
        cnt += __popcll(bal);
    }
    if (cnt < POST_NMS_) {
        for (int c = 0; c < NWORDS_ && cnt < POST_NMS_; c++) {
            int j = c * 64 + lane;
            bool k = (j < PRE_NMS_) && !(keep[j] && (sc[j] > -5e8f));
            unsigned long long bal = __ballot(k);
            int pos = cnt + __popcll(bal & lmask);
            if (k && pos < POST_NMS_) sel[pos] = j;
            cnt += __popcll(bal);
        }
    }
    __syncthreads();
    for (int i = lane; i < POST_NMS_; i += 64) {
        int j = sel[i];
        float4 b = nb[j];
        out[i * 5 + 0] = 0.f;
        out[i * 5 + 1] = b.x;
        out[i * 5 + 2] = b.y;
        out[i * 5 + 3] = b.z;
        out[i * 5 + 4] = b.w;
    }
}

// ---------------------------------------------------------------------------
extern "C" void kernel_launch(void* const* d_in, const int* in_sizes, int n_in,
                              void* d_out, int out_size, void* d_ws, size_t ws_size,
                              hipStream_t stream)
{
    const float* fm      = (const float*)d_in[0];
    const float* im_info = (const float*)d_in[1];
    const float* conv_w  = (const float*)d_in[2];
    const float* conv_b  = (const float*)d_in[3];
    const float* cls_w   = (const float*)d_in[4];
    const float* cls_b   = (const float*)d_in[5];
    const float* bbox_w  = (const float*)d_in[6];
    const float* bbox_b  = (const float*)d_in[7];
    float* out = (float*)d_out;

    char* ws = (char*)d_ws;
    size_t off = 0;
    auto alloc = [&](size_t bytes) -> void* {
        void* p = ws + off;
        off = (off + bytes + 255) & ~(size_t)255;
        return p;
    };
    float* xt                 = (float*)alloc((size_t)HW_ * 512 * 4);          // 31.1 MB
    float* scores             = (float*)alloc((size_t)NA_ * 4);                // 0.55 MB
    float4* boxes             = (float4*)alloc((size_t)NA_ * 16);              // 2.2 MB
    unsigned long long* keys  = (unsigned long long*)alloc((size_t)NSORT_ * 8);// 2.1 MB
    float4* nb                = (float4*)alloc((size_t)NB_PAD_ * 16);
    float* sc                 = (float*)alloc((size_t)NB_PAD_ * 4);
    float* area               = (float*)alloc((size_t)NB_PAD_ * 4);
    unsigned long long* mask  = (unsigned long long*)alloc((size_t)NB_PAD_ * NWORDS_ * 8); // 4.5 MB
    unsigned long long* diag  = (unsigned long long*)alloc((size_t)NB_PAD_ * 8);
    int* keep                 = (int*)alloc((size_t)NB_PAD_ * 4);

    conv3x3_relu<<<dim3(5, 25, 4), 256, 0, stream>>>(fm, conv_w, conv_b, xt);
    rpn_head<<<dim3(950), 256, 0, stream>>>(xt, cls_w, cls_b, bbox_w, bbox_b,
                                            im_info, scores, boxes);
    build_keys<<<dim3(NSORT_ / 256), 256, 0, stream>>>(scores, keys);
    bitonic_local_sort<<<dim3(NSORT_ / 4096), 256, 0, stream>>>(keys);
    for (int k = 8192; k <= NSORT_; k <<= 1) {
        for (int j = k >> 1; j >= 4096; j >>= 1)
            bitonic_global<<<dim3(NSORT_ / 2 / 256), 256, 0, stream>>>(keys, j, k);
        bitonic_local_merge<<<dim3(NSORT_ / 4096), 256, 0, stream>>>(keys, k);
    }
    gather_top<<<dim3((NB_PAD_ + 255) / 256), 256, 0, stream>>>(keys, scores, boxes,
                                                                nb, sc, area);
    nms_mask<<<dim3(NWORDS_, NWORDS_), 64, 0, stream>>>(nb, area, mask, diag);
    nms_scan<<<dim3(1), 256, 0, stream>>>(mask, diag, keep);
    final_out<<<dim3(1), 64, 0, stream>>>(keep, sc, nb, out);
}

// Round 3
// 1566.569 us; speedup vs baseline: 2.0014x; 1.1311x over previous
//
#include <hip/hip_runtime.h>
#include <hip/hip_bf16.h>
#include <math.h>

#define H_ 100
#define W_ 152
#define HW_ 15200
#define C_ 512
#define A_ 9
#define NA_ 136800        // HW*A
#define NSORT_ 262144     // 2^18 >= NA
#define PRE_NMS_ 6000
#define NB_PAD_ 6016      // PRE_NMS padded to 64
#define NWORDS_ 94        // ceil(6000/64)
#define POST_NMS_ 300

// ---------------------------------------------------------------------------
// Kernel 1: 3x3 conv (SAME) + bias + ReLU, fp32.  v2:
//  - staging index math hoisted out of the K-loop (7 descriptors/thread,
//    strength-reduced pointer increments)
//  - ci-group of 8 (half the barriers), LDS 44.5 KB
//  - explicit float4 LDS window reads
//  - launch_bounds(256,2) so win/wv stay in registers
// FMA chain order per output (ci asc, dy, dx) identical to v1 -> bitwise-same.
// Output transposed: xt[p][co], p = h*W+w.
// ---------------------------------------------------------------------------
__global__ __launch_bounds__(256, 2) void conv3x3_relu(
    const float* __restrict__ fm, const float* __restrict__ cw,
    const float* __restrict__ cb, float* __restrict__ xt)
{
    __shared__ float in_lds[8][6][40];    // 7.7 KB  [ci][row+halo][col+halo]
    __shared__ float w_lds[72][128];      // 36.9 KB [ci*9+tap][co]

    const int tid = threadIdx.x;
    const int w0 = blockIdx.x * 32;
    const int h0 = blockIdx.y * 4;
    const int co_base = blockIdx.z * 128;
    const int co_grp = tid & 31;          // 0..31 -> co0 = 4*co_grp
    const int pos_grp = tid >> 5;         // 0..7
    const int r = pos_grp & 3;            // row within tile
    const int ch16 = (pos_grp >> 2) * 16; // col-half base

    // ---- hoisted input-staging descriptors: 1632 = 8ci*6row*34col ----
    int ld_lds[7];
    const float* ld_gp[7];
    bool ld_ok[7];
#pragma unroll
    for (int k = 0; k < 7; k++) {
        int idx = tid + k * 256;
        bool act = idx < 1632;
        int i2 = act ? idx : 0;
        int ci = i2 / 204;
        int rem = i2 - ci * 204;
        int rr = rem / 34;
        int cl = rem - rr * 34;
        int hh = h0 + rr - 1;
        int ww = w0 + cl - 1;
        bool ok = act && (hh >= 0) && (hh < H_) && (ww >= 0) && (ww < W_);
        ld_ok[k] = ok;
        ld_lds[k] = act ? ((ci * 6 + rr) * 40 + cl) : -1;
        ld_gp[k] = fm + ((size_t)ci * HW_ + (ok ? (hh * W_ + ww) : 0));
    }

    // ---- hoisted weight-staging descriptors: 72 floats x 128 co per group ----
    const int wco = tid >> 1;             // 0..127
    const int whalf = tid & 1;            // floats [whalf*36, whalf*36+36)
    const float* wg = cw + (size_t)(co_base + wco) * 4608 + whalf * 36;
    float* wl = &w_lds[whalf * 36][wco];  // row stride 128 floats

    float acc[4][16];
#pragma unroll
    for (int a = 0; a < 4; a++)
#pragma unroll
        for (int j = 0; j < 16; j++) acc[a][j] = 0.f;

    for (int ci0 = 0; ci0 < 512; ci0 += 8) {
        __syncthreads();
        // stage input (loads unconditional from clamped addr, select 0)
#pragma unroll
        for (int k = 0; k < 7; k++) {
            float v = ld_gp[k][0];
            v = ld_ok[k] ? v : 0.f;
            if (ld_lds[k] >= 0) ((float*)in_lds)[ld_lds[k]] = v;
            ld_gp[k] += 8 * HW_;
        }
        // stage weights: 9 aligned float4 loads, 36 static ds_writes
#pragma unroll
        for (int g = 0; g < 9; g++) {
            float4 v = *(const float4*)(wg + g * 4);
            wl[(g * 4 + 0) * 128] = v.x;
            wl[(g * 4 + 1) * 128] = v.y;
            wl[(g * 4 + 2) * 128] = v.z;
            wl[(g * 4 + 3) * 128] = v.w;
        }
        wg += 72;
        __syncthreads();

#pragma unroll
        for (int cc = 0; cc < 8; cc++) {
            float4 wv[9];
#pragma unroll
            for (int kk = 0; kk < 9; kk++)
                wv[kk] = *(const float4*)&w_lds[cc * 9 + kk][co_grp * 4];
#pragma unroll
            for (int dy = 0; dy < 3; dy++) {
                const float* rowp = &in_lds[cc][r + dy][ch16];
                float win[18];
                *(float4*)&win[0]  = *(const float4*)&rowp[0];
                *(float4*)&win[4]  = *(const float4*)&rowp[4];
                *(float4*)&win[8]  = *(const float4*)&rowp[8];
                *(float4*)&win[12] = *(const float4*)&rowp[12];
                win[16] = rowp[16];
                win[17] = rowp[17];
#pragma unroll
                for (int dx = 0; dx < 3; dx++) {
                    float4 wk = wv[dy * 3 + dx];
#pragma unroll
                    for (int j = 0; j < 16; j++) {
                        float iv = win[j + dx];
                        acc[0][j] = fmaf(iv, wk.x, acc[0][j]);
                        acc[1][j] = fmaf(iv, wk.y, acc[1][j]);
                        acc[2][j] = fmaf(iv, wk.z, acc[2][j]);
                        acc[3][j] = fmaf(iv, wk.w, acc[3][j]);
                    }
                }
            }
        }
    }

    const int co0 = co_base + co_grp * 4;
    const float4 bias = *(const float4*)(cb + co0);
    const int hh = h0 + r;
#pragma unroll
    for (int j = 0; j < 16; j++) {
        int ww = w0 + ch16 + j;
        if (ww < W_) {
            float4 o;
            o.x = fmaxf(acc[0][j] + bias.x, 0.f);
            o.y = fmaxf(acc[1][j] + bias.y, 0.f);
            o.z = fmaxf(acc[2][j] + bias.z, 0.f);
            o.w = fmaxf(acc[3][j] + bias.w, 0.f);
            *(float4*)(xt + (size_t)(hh * W_ + ww) * 512 + co0) = o;
        }
    }
}

// ---------------------------------------------------------------------------
// Kernel 2: 1x1 convs (cls 18ch + bbox 36ch) + softmax fg + anchors + bbox
// transform + clip + min-size filter. One block = 16 positions.
// ---------------------------------------------------------------------------
__device__ const float g_bx1[9] = {-84.f,-176.f,-360.f,-56.f,-120.f,-248.f,-36.f,-80.f,-168.f};
__device__ const float g_by1[9] = {-40.f,-88.f,-184.f,-56.f,-120.f,-248.f,-80.f,-168.f,-344.f};
__device__ const float g_bx2[9] = {99.f,191.f,375.f,71.f,135.f,263.f,51.f,95.f,183.f};
__device__ const float g_by2[9] = {55.f,103.f,199.f,71.f,135.f,263.f,95.f,183.f,359.f};

__global__ __launch_bounds__(256) void rpn_head(
    const float* __restrict__ xt,
    const float* __restrict__ cls_w, const float* __restrict__ cls_b,
    const float* __restrict__ bbox_w, const float* __restrict__ bbox_b,
    const float* __restrict__ im_info,
    float* __restrict__ scores, float4* __restrict__ boxes)
{
    __shared__ float xl[16 * 512];
    __shared__ float raw[16][56];
    const int tid = threadIdx.x;
    const int p0 = blockIdx.x * 16;

    {
        const float4* src = (const float4*)(xt + (size_t)p0 * 512);
        float4* dst = (float4*)xl;
        for (int i = tid; i < 2048; i += 256) dst[i] = src[i];
    }
    __syncthreads();

    if (tid < 216) {
        int c  = tid % 54;
        int pg = tid / 54;               // 0..3, 4 positions each
        const float* wrow = (c < 18) ? (cls_w + (size_t)c * 512)
                                     : (bbox_w + (size_t)(c - 18) * 512);
        float b = (c < 18) ? cls_b[c] : bbox_b[c - 18];
        float a0 = b, a1 = b, a2 = b, a3 = b;
        const float* x0 = xl + (size_t)(pg * 4) * 512;
        for (int ci = 0; ci < 512; ci++) {
            float wv = wrow[ci];
            a0 = fmaf(wv, x0[ci], a0);
            a1 = fmaf(wv, x0[512 + ci], a1);
            a2 = fmaf(wv, x0[1024 + ci], a2);
            a3 = fmaf(wv, x0[1536 + ci], a3);
        }
        raw[pg * 4 + 0][c] = a0;
        raw[pg * 4 + 1][c] = a1;
        raw[pg * 4 + 2][c] = a2;
        raw[pg * 4 + 3][c] = a3;
    }
    __syncthreads();

    if (tid < 144) {
        int pos = tid / 9;
        int a   = tid % 9;
        int p = p0 + pos;
        int hh = p / 152;
        int ww = p - hh * 152;

        float s0 = raw[pos][a], s1 = raw[pos][9 + a];
        float fg = 1.f / (1.f + expf(s0 - s1));

        float dx = raw[pos][18 + 4 * a + 0];
        float dy = raw[pos][18 + 4 * a + 1];
        float dw = raw[pos][18 + 4 * a + 2];
        float dh = raw[pos][18 + 4 * a + 3];

        float sx = ww * 16.f, sy = hh * 16.f;
        float ax1 = g_bx1[a] + sx, ay1 = g_by1[a] + sy;
        float ax2 = g_bx2[a] + sx, ay2 = g_by2[a] + sy;
        float aw = ax2 - ax1 + 1.f, ah = ay2 - ay1 + 1.f;
        float axc = ax1 + 0.5f * aw, ayc = ay1 + 0.5f * ah;

        float px = dx * aw + axc, py = dy * ah + ayc;
        float pw = expf(dw) * aw, ph = expf(dh) * ah;
        float x1 = px - 0.5f * pw, y1 = py - 0.5f * ph;
        float x2 = px + 0.5f * pw, y2 = py + 0.5f * ph;

        float imh = im_info[0], imw = im_info[1], scl = im_info[2];
        x1 = fminf(fmaxf(x1, 0.f), imw - 1.f);
        y1 = fminf(fmaxf(y1, 0.f), imh - 1.f);
        x2 = fminf(fmaxf(x2, 0.f), imw - 1.f);
        y2 = fminf(fmaxf(y2, 0.f), imh - 1.f);

        float wd = x2 - x1 + 1.f, hd = y2 - y1 + 1.f;
        bool valid = (wd >= 16.f * scl) && (hd >= 16.f * scl);

        int idx = p * 9 + a;
        scores[idx] = valid ? fg : -1000000000.f;
        boxes[idx] = make_float4(x1, y1, x2, y2);
    }
}

// ---------------------------------------------------------------------------
// Top-K: exact bitonic sort (descending) of u64 keys (sortable_score, ~index)
// ---------------------------------------------------------------------------
__global__ void build_keys(const float* __restrict__ scores,
                           unsigned long long* __restrict__ keys)
{
    int i = blockIdx.x * 256 + threadIdx.x;
    if (i >= NSORT_) return;
    unsigned long long k = 0ull;
    if (i < NA_) {
        unsigned u = __float_as_uint(scores[i]);
        u = (u & 0x80000000u) ? ~u : (u | 0x80000000u);
        k = ((unsigned long long)u << 32) | (unsigned)(0xFFFFFFFFu - (unsigned)i);
    }
    keys[i] = k;
}

__device__ __forceinline__ void cex(unsigned long long* s, int i, int l, bool desc)
{
    unsigned long long a = s[i], b = s[l];
    if (desc ? (a < b) : (a > b)) { s[i] = b; s[l] = a; }
}

__global__ __launch_bounds__(256) void bitonic_local_sort(unsigned long long* __restrict__ keys)
{
    __shared__ unsigned long long s[4096];
    const int tid = threadIdx.x;
    const int base = blockIdx.x * 4096;
    for (int i = tid; i < 4096; i += 256) s[i] = keys[base + i];
    __syncthreads();
    for (int k = 2; k <= 4096; k <<= 1) {
        for (int j = k >> 1; j > 0; j >>= 1) {
#pragma unroll
            for (int m = 0; m < 8; m++) {
                int p = tid + m * 256;
                int i = ((p & ~(j - 1)) << 1) | (p & (j - 1));
                int l = i | j;
                bool desc = (((base + i) & k) == 0);
                cex(s, i, l, desc);
            }
            __syncthreads();
        }
    }
    for (int i = tid; i < 4096; i += 256) keys[base + i] = s[i];
}

__global__ void bitonic_global(unsigned long long* __restrict__ keys, int j, int k)
{
    int p = blockIdx.x * 256 + threadIdx.x;      // pair index
    int i = ((p & ~(j - 1)) << 1) | (p & (j - 1));
    int l = i | j;
    bool desc = ((i & k) == 0);
    unsigned long long a = keys[i], b = keys[l];
    if (desc ? (a < b) : (a > b)) { keys[i] = b; keys[l] = a; }
}

__global__ __launch_bounds__(256) void bitonic_local_merge(unsigned long long* __restrict__ keys, int k)
{
    __shared__ unsigned long long s[4096];
    const int tid = threadIdx.x;
    const int base = blockIdx.x * 4096;
    const bool desc = ((base & k) == 0);     // uniform for k >= 8192
    for (int i = tid; i < 4096; i += 256) s[i] = keys[base + i];
    __syncthreads();
    for (int j = 2048; j > 0; j >>= 1) {
#pragma unroll
        for (int m = 0; m < 8; m++) {
            int p = tid + m * 256;
            int i = ((p & ~(j - 1)) << 1) | (p & (j - 1));
            cex(s, i, i | j, desc);
        }
        __syncthreads();
    }
    for (int i = tid; i < 4096; i += 256) keys[base + i] = s[i];
}

// ---------------------------------------------------------------------------
// Gather top-6000 (padded to 6016) boxes/scores/areas in sorted order
// ---------------------------------------------------------------------------
__global__ void gather_top(const unsigned long long* __restrict__ keys,
                           const float* __restrict__ scores,
                           const float4* __restrict__ boxes,
                           float4* __restrict__ nb, float* __restrict__ sc,
                           float* __restrict__ area)
{
    int r = blockIdx.x * 256 + threadIdx.x;
    if (r >= NB_PAD_) return;
    if (r < PRE_NMS_) {
        unsigned long long key = keys[r];
        unsigned idx = 0xFFFFFFFFu - (unsigned)(key & 0xFFFFFFFFull);
        float4 b = boxes[idx];
        nb[r] = b;
        sc[r] = scores[idx];
        area[r] = (b.z - b.x + 1.f) * (b.w - b.y + 1.f);
    } else {
        nb[r] = make_float4(0.f, 0.f, 0.f, 0.f);
        sc[r] = -1000000000.f;
        area[r] = 1.f;
    }
}

// ---------------------------------------------------------------------------
// NMS suppression bitmatrix: mask[i][cb] bit b = (j=cb*64+b suppressed by i)
// diag[i] = the diagonal-block word (for the scan's intra-block resolution).
// ---------------------------------------------------------------------------
__global__ __launch_bounds__(64) void nms_mask(const float4* __restrict__ nb,
                                               const float* __restrict__ area,
                                               unsigned long long* __restrict__ mask,
                                               unsigned long long* __restrict__ diag)
{
    __shared__ float4 cbox[64];
    __shared__ float carea[64];
    const int t = threadIdx.x;
    const int cbk = blockIdx.x, rb = blockIdx.y;
    const int jBase = cbk * 64;
    cbox[t] = nb[jBase + t];
    carea[t] = area[jBase + t];
    __syncthreads();

    const int i = rb * 64 + t;
    const float4 bi = nb[i];
    const float ai = area[i];
    unsigned long long bits = 0ull;
#pragma unroll 8
    for (int b = 0; b < 64; b++) {
        int j = jBase + b;
        if (j > i) {
            float4 bj = cbox[b];
            float xx1 = fmaxf(bi.x, bj.x), yy1 = fmaxf(bi.y, bj.y);
            float xx2 = fminf(bi.z, bj.z), yy2 = fminf(bi.w, bj.w);
            float iw = fmaxf(0.f, xx2 - xx1 + 1.f);
            float ih = fmaxf(0.f, yy2 - yy1 + 1.f);
            float inter = iw * ih;
            float iou = inter / (ai + carea[b] - inter);
            if (iou > 0.7f) bits |= (1ull << b);
        }
    }
    mask[(size_t)i * NWORDS_ + cbk] = bits;
    if (cbk == rb) diag[i] = bits;
}

// ---------------------------------------------------------------------------
// Block-serial NMS scan v3: 4 waves.
//  - shared remv bitset (rlo/rhi) in LDS; ext = remv[c] broadcast read
//  - wave w speculatively loads mask rows for candidate bits [16w,16w+16) of
//    the PRE-resolution superset (~ext) -> loads overlap wave0's scalar
//    intra-block resolution (diag words, readlane chain)
//  - post-barrier: OR rows predicated on the resolved alive set, merge via
//    LDS atomics
// ---------------------------------------------------------------------------
__device__ __forceinline__ unsigned long long readlane_u64(unsigned long long v, int l)
{
    unsigned int lo = (unsigned int)__builtin_amdgcn_readlane((int)(unsigned int)(v & 0xffffffffull), l);
    unsigned int hi = (unsigned int)__builtin_amdgcn_readlane((int)(unsigned int)(v >> 32), l);
    return ((unsigned long long)hi << 32) | (unsigned long long)lo;
}

__global__ __launch_bounds__(256) void nms_scan(const unsigned long long* __restrict__ mask,
                                                const unsigned long long* __restrict__ diag,
                                                int* __restrict__ keep)
{
    __shared__ unsigned long long dlds[NB_PAD_];   // 48.1 KB
    __shared__ unsigned rlo[NWORDS_], rhi[NWORDS_];
    __shared__ unsigned long long aliveSh;
    const int tid = threadIdx.x;
    const int wave = tid >> 6, lane = tid & 63;

    for (int i = tid; i < NB_PAD_; i += 256) dlds[i] = diag[i];
    if (tid < NWORDS_) { rlo[tid] = 0u; rhi[tid] = 0u; }
    __syncthreads();

    for (int c = 0; c < NWORDS_; c++) {
        unsigned long long ext = ((unsigned long long)rhi[c] << 32) | (unsigned long long)rlo[c];
        unsigned long long aliveP = ~ext;                     // pre-resolution superset

        // extract my wave's candidate bits (wave-uniform scalar loop, <=16)
        unsigned long long mysel = aliveP & (0xFFFFull << (wave * 16));
        int rb[16];
        int n = 0;
        while (mysel) { rb[n++] = (int)__builtin_ctzll(mysel); mysel &= mysel - 1; }

        // issue speculative row loads (in flight during resolution)
        unsigned long long v0[16], v1[16];
#pragma unroll
        for (int i = 0; i < 16; i++) {
            if (i < n) {
                const unsigned long long* row = mask + (size_t)(c * 64 + rb[i]) * NWORDS_;
                v0[i] = row[lane];
                v1[i] = (lane < NWORDS_ - 64) ? row[64 + lane] : 0ull;
            }
        }

        if (wave == 0) {
            unsigned long long myD = dlds[c * 64 + lane];
            unsigned long long alive = aliveP, todo = aliveP;
            while (todo) {
                int l = (int)__builtin_ctzll(todo);
                todo &= todo - 1;
                unsigned long long d = readlane_u64(myD, l);
                alive &= ~d;
                todo &= ~d;
            }
            keep[c * 64 + lane] = (int)((alive >> lane) & 1ull);
            if (lane == 0) aliveSh = alive;
        }
        __syncthreads();

        unsigned long long alive = aliveSh;
        unsigned long long d0 = 0ull, d1 = 0ull;
#pragma unroll
        for (int i = 0; i < 16; i++) {
            if (i < n && ((alive >> rb[i]) & 1ull)) { d0 |= v0[i]; d1 |= v1[i]; }
        }
        if (d0) {
            atomicOr(&rlo[lane], (unsigned)d0);
            atomicOr(&rhi[lane], (unsigned)(d0 >> 32));
        }
        if (lane < NWORDS_ - 64 && d1) {
            atomicOr(&rlo[64 + lane], (unsigned)d1);
            atomicOr(&rhi[64 + lane], (unsigned)(d1 >> 32));
        }
        __syncthreads();
    }
}

// ---------------------------------------------------------------------------
// Final: top-300 of kept (then non-kept in index order to fill) -> rois
// ---------------------------------------------------------------------------
__global__ __launch_bounds__(64) void final_out(const int* __restrict__ keep,
                                                const float* __restrict__ sc,
                                                const float4* __restrict__ nb,
                                                float* __restrict__ out)
{
    __shared__ int sel[POST_NMS_];
    const int lane = threadIdx.x;
    const unsigned long long lmask = (lane == 0) ? 0ull : ((~0ull) >> (64 - lane));

    int cnt = 0;
    for (int c = 0; c < NWORDS_ && cnt < POST_NMS_; c++) {
        int j = c * 64 + lane;
        bool k = (j < PRE_NMS_) && keep[j] && (sc[j] > -5e8f);
        unsigned long long bal = __ballot(k);
        int pos = cnt + __popcll(bal & lmask);
        if (k && pos < POST_NMS_) sel[pos] = j;
        cnt += __popcll(bal);
    }
    if (cnt < POST_NMS_) {
        for (int c = 0; c < NWORDS_ && cnt < POST_NMS_; c++) {
            int j = c * 64 + lane;
            bool k = (j < PRE_NMS_) && !(keep[j] && (sc[j] > -5e8f));
            unsigned long long bal = __ballot(k);
            int pos = cnt + __popcll(bal & lmask);
            if (k && pos < POST_NMS_) sel[pos] = j;
            cnt += __popcll(bal);
        }
    }
    __syncthreads();
    for (int i = lane; i < POST_NMS_; i += 64) {
        int j = sel[i];
        float4 b = nb[j];
        out[i * 5 + 0] = 0.f;
        out[i * 5 + 1] = b.x;
        out[i * 5 + 2] = b.y;
        out[i * 5 + 3] = b.z;
        out[i * 5 + 4] = b.w;
    }
}

// ---------------------------------------------------------------------------
extern "C" void kernel_launch(void* const* d_in, const int* in_sizes, int n_in,
                              void* d_out, int out_size, void* d_ws, size_t ws_size,
                              hipStream_t stream)
{
    const float* fm      = (const float*)d_in[0];
    const float* im_info = (const float*)d_in[1];
    const float* conv_w  = (const float*)d_in[2];
    const float* conv_b  = (const float*)d_in[3];
    const float* cls_w   = (const float*)d_in[4];
    const float* cls_b   = (const float*)d_in[5];
    const float* bbox_w  = (const float*)d_in[6];
    const float* bbox_b  = (const float*)d_in[7];
    float* out = (float*)d_out;

    char* ws = (char*)d_ws;
    size_t off = 0;
    auto alloc = [&](size_t bytes) -> void* {
        void* p = ws + off;
        off = (off + bytes + 255) & ~(size_t)255;
        return p;
    };
    float* xt                 = (float*)alloc((size_t)HW_ * 512 * 4);          // 31.1 MB
    float* scores             = (float*)alloc((size_t)NA_ * 4);                // 0.55 MB
    float4* boxes             = (float4*)alloc((size_t)NA_ * 16);              // 2.2 MB
    unsigned long long* keys  = (unsigned long long*)alloc((size_t)NSORT_ * 8);// 2.1 MB
    float4* nb                = (float4*)alloc((size_t)NB_PAD_ * 16);
    float* sc                 = (float*)alloc((size_t)NB_PAD_ * 4);
    float* area               = (float*)alloc((size_t)NB_PAD_ * 4);
    unsigned long long* mask  = (unsigned long long*)alloc((size_t)NB_PAD_ * NWORDS_ * 8); // 4.5 MB
    unsigned long long* diag  = (unsigned long long*)alloc((size_t)NB_PAD_ * 8);
    int* keep                 = (int*)alloc((size_t)NB_PAD_ * 4);

    conv3x3_relu<<<dim3(5, 25, 4), 256, 0, stream>>>(fm, conv_w, conv_b, xt);
    rpn_head<<<dim3(950), 256, 0, stream>>>(xt, cls_w, cls_b, bbox_w, bbox_b,
                                            im_info, scores, boxes);
    build_keys<<<dim3(NSORT_ / 256), 256, 0, stream>>>(scores, keys);
    bitonic_local_sort<<<dim3(NSORT_ / 4096), 256, 0, stream>>>(keys);
    for (int k = 8192; k <= NSORT_; k <<= 1) {
        for (int j = k >> 1; j >= 4096; j >>= 1)
            bitonic_global<<<dim3(NSORT_ / 2 / 256), 256, 0, stream>>>(keys, j, k);
        bitonic_local_merge<<<dim3(NSORT_ / 4096), 256, 0, stream>>>(keys, k);
    }
    gather_top<<<dim3((NB_PAD_ + 255) / 256), 256, 0, stream>>>(keys, scores, boxes,
                                                                nb, sc, area);
    nms_mask<<<dim3(NWORDS_, NWORDS_), 64, 0, stream>>>(nb, area, mask, diag);
    nms_scan<<<dim3(1), 256, 0, stream>>>(mask, diag, keep);
    final_out<<<dim3(1), 64, 0, stream>>>(keep, sc, nb, out);
}

// Round 5
// 1276.164 us; speedup vs baseline: 2.4568x; 1.2276x over previous
//
#include <hip/hip_runtime.h>
#include <hip/hip_bf16.h>
#include <math.h>

#define H_ 100
#define W_ 152
#define HW_ 15200
#define C_ 512
#define A_ 9
#define NA_ 136800        // HW*A
#define NSORT_ 262144     // 2^18 >= NA
#define PRE_NMS_ 6000
#define NB_PAD_ 6016      // PRE_NMS padded to 64
#define NWORDS_ 94        // ceil(6000/64)
#define POST_NMS_ 300

#define QH_ 102           // padded rows
#define QW_ 154           // padded cols
#define NQ_ (QH_ * QW_)   // 15708 padded positions

typedef __attribute__((ext_vector_type(8))) short short8;   // 8 bf16 (4 VGPRs)
typedef __attribute__((ext_vector_type(4))) float f32x4;    // MFMA C/D

// ---------------------------------------------------------------------------
// pack_x: fm (fp32 CHW) -> padded HWC bf16 3-term split arrays xp{h,m,l}.
// x = h + m + l with h=bf16(x), m=bf16(x-h), l=bf16(x-h-m)  (24 mantissa bits,
// residual ~2^-27). Border rows/cols are zero -> conv taps need no masking.
// ---------------------------------------------------------------------------
__global__ __launch_bounds__(256) void pack_x(const float* __restrict__ fm,
                                              __hip_bfloat16* __restrict__ xph,
                                              __hip_bfloat16* __restrict__ xpm,
                                              __hip_bfloat16* __restrict__ xpl)
{
    __shared__ float t[64][65];
    const int tid = threadIdx.x;
    const int q0 = blockIdx.x * 64;
    const int c0 = blockIdx.y * 64;

    // phase 1: read fm coalesced over q (lanes = q), write LDS [ci][q]
    {
        const int qi = tid & 63;
        const int cs = tid >> 6;          // 0..3
        const int q = q0 + qi;
        int hp = q / QW_, wp = q - hp * QW_;
        bool inter = (q < NQ_) && (hp >= 1) && (hp <= 100) && (wp >= 1) && (wp <= 152);
        int p = inter ? ((hp - 1) * W_ + (wp - 1)) : 0;
#pragma unroll
        for (int cc = cs; cc < 64; cc += 4) {
            float v = inter ? fm[(size_t)(c0 + cc) * HW_ + p] : 0.f;
            t[cc][qi] = v;
        }
    }
    __syncthreads();
    // phase 2: write coalesced over ci (lanes = ci)
    {
        const int cl = tid & 63;
        const int qs = tid >> 6;
#pragma unroll
        for (int qq = qs; qq < 64; qq += 4) {
            int qg = q0 + qq;
            if (qg < NQ_) {
                float v = t[cl][qq];
                __hip_bfloat16 h = __float2bfloat16(v);
                float r1 = v - __bfloat162float(h);
                __hip_bfloat16 m = __float2bfloat16(r1);
                float r2 = r1 - __bfloat162float(m);
                __hip_bfloat16 l = __float2bfloat16(r2);
                size_t o = (size_t)qg * 512 + c0 + cl;
                xph[o] = h;
                xpm[o] = m;
                xpl[o] = l;
            }
        }
    }
}

// ---------------------------------------------------------------------------
// pack_w: cw[co][ci][3][3] fp32 -> MFMA B-fragment-ordered bf16 3-term split.
// Layout: [t9][k32][n16][lane(64)][8]; element for lane L, j:
//   B[k = k32*32 + (L>>4)*8 + j][n = n16*16 + (L&15)] = cw[n][k][ky][kx]
// ---------------------------------------------------------------------------
__global__ __launch_bounds__(256) void pack_w(const float* __restrict__ cw,
                                              __hip_bfloat16* __restrict__ bph,
                                              __hip_bfloat16* __restrict__ bpm,
                                              __hip_bfloat16* __restrict__ bpl)
{
    int id = blockIdx.x * 256 + threadIdx.x;      // 294912 total
    int lane = id & 63;
    int rest = id >> 6;
    int n16 = rest & 31;
    int tk = rest >> 5;
    int k32 = tk & 15;
    int t9 = tk >> 4;
    if (t9 >= 9) return;
    int ky = t9 / 3, kx = t9 - ky * 3;
    int n = n16 * 16 + (lane & 15);
    int kb = k32 * 32 + (lane >> 4) * 8;

    union H8 { short8 s; __hip_bfloat16 b[8]; } hv, mv, lv;
#pragma unroll
    for (int j = 0; j < 8; j++) {
        int ci = kb + j;
        float v = cw[(((size_t)n * 512 + ci) * 3 + ky) * 3 + kx];
        __hip_bfloat16 h = __float2bfloat16(v);
        float r1 = v - __bfloat162float(h);
        __hip_bfloat16 m = __float2bfloat16(r1);
        float r2 = r1 - __bfloat162float(m);
        hv.b[j] = h;
        mv.b[j] = m;
        lv.b[j] = __float2bfloat16(r2);
    }
    *(short8*)((short*)bph + (size_t)id * 8) = hv.s;
    *(short8*)((short*)bpm + (size_t)id * 8) = mv.s;
    *(short8*)((short*)bpl + (size_t)id * 8) = lv.s;
}

// ---------------------------------------------------------------------------
// conv_mfma: 3x3 conv as 9-tap implicit GEMM, bf16 3-TERM split, fp32 acc.
// Products kept: hh + hm + mh + hl + lh + mm  (error ~2^-27 per operand).
// Block = 128m x 128n, 4 waves in 2x2; wave owns 64m x 64n (4x4 frags).
// LDS per k32: A 24 slots [mf*3+arr], B 24 slots [nf*3+arr], each [64][8]
// shorts -> all LDS traffic is lane-major 16B (conflict-free). 48 KB total.
// Epilogue: + bias, relu, store xt[p][co] fp32 (layout rpn_head consumes).
// ---------------------------------------------------------------------------
__global__ __launch_bounds__(256, 2) void conv_mfma(
    const __hip_bfloat16* __restrict__ xph, const __hip_bfloat16* __restrict__ xpm,
    const __hip_bfloat16* __restrict__ xpl,
    const __hip_bfloat16* __restrict__ bph, const __hip_bfloat16* __restrict__ bpm,
    const __hip_bfloat16* __restrict__ bpl,
    const float* __restrict__ cb, float* __restrict__ xt)
{
    __shared__ short a_lds[24][64][8];   // 24 KB, slot = mf*3 + arr
    __shared__ short b_lds[24][64][8];   // 24 KB, slot = nf*3 + arr

    const int tid = threadIdx.x;
    const int wave = tid >> 6, lane = tid & 63;
    const int wm = wave >> 1, wn = wave & 1;
    const int mb = blockIdx.x, nb = blockIdx.y;

    const __hip_bfloat16* xarr[3] = {xph, xpm, xpl};
    const __hip_bfloat16* barr[3] = {bph, bpm, bpl};

    // staging descriptors: thread handles slots s = (tid>>6)*6 + i, i<6
    const int ala = tid & 63;
    const int sg = tid >> 6;
    const short* aSrc[6];
    const short* bSrc[6];
    int sBase = sg * 6;
#pragma unroll
    for (int i = 0; i < 6; i++) {
        int s = sBase + i;                // 0..23
        int f = s / 3, arr = s - 3 * (s / 3);
        // A: m = mb*128 + f*16 + (ala&15), k-chunk = (ala>>4)*8
        int m = mb * 128 + f * 16 + (ala & 15);
        int hh = m / W_, ww = m - hh * W_;
        int q = (hh + 1) * QW_ + (ww + 1);
        aSrc[i] = (const short*)xarr[arr] + (size_t)q * 512 + (ala >> 4) * 8;
        // B: n16 = nb*8 + f, lane-major 8 shorts
        bSrc[i] = (const short*)barr[arr] + (size_t)(nb * 8 + f) * 512 + ala * 8;
    }

    f32x4 acc[4][4];
#pragma unroll
    for (int f = 0; f < 4; f++)
#pragma unroll
        for (int g = 0; g < 4; g++)
            acc[f][g] = (f32x4){0.f, 0.f, 0.f, 0.f};

    for (int t9 = 0; t9 < 9; t9++) {
        const int dy = t9 / 3 - 1, dx = t9 - (t9 / 3) * 3 - 1;
        const int qoff512 = (dy * QW_ + dx) * 512;
        for (int k32 = 0; k32 < 16; k32++) {
            const int offA = qoff512 + k32 * 32;
            const int offB = (t9 * 16 + k32) * 16384;
            __syncthreads();
#pragma unroll
            for (int i = 0; i < 6; i++)
                *(short8*)&a_lds[sBase + i][ala][0] = *(const short8*)(aSrc[i] + offA);
#pragma unroll
            for (int i = 0; i < 6; i++)
                *(short8*)&b_lds[sBase + i][ala][0] = *(const short8*)(bSrc[i] + offB);
            __syncthreads();

            short8 ah[4], am[4], al[4];
#pragma unroll
            for (int f = 0; f < 4; f++) {
                ah[f] = *(const short8*)&a_lds[(wm * 4 + f) * 3 + 0][lane][0];
                am[f] = *(const short8*)&a_lds[(wm * 4 + f) * 3 + 1][lane][0];
                al[f] = *(const short8*)&a_lds[(wm * 4 + f) * 3 + 2][lane][0];
            }
#pragma unroll
            for (int g = 0; g < 4; g++) {
                short8 bh = *(const short8*)&b_lds[(wn * 4 + g) * 3 + 0][lane][0];
                short8 bm = *(const short8*)&b_lds[(wn * 4 + g) * 3 + 1][lane][0];
                short8 bl = *(const short8*)&b_lds[(wn * 4 + g) * 3 + 2][lane][0];
#pragma unroll
                for (int f = 0; f < 4; f++) {
                    f32x4 a = acc[f][g];
                    a = __builtin_amdgcn_mfma_f32_16x16x32_bf16(ah[f], bh, a, 0, 0, 0);
                    a = __builtin_amdgcn_mfma_f32_16x16x32_bf16(ah[f], bm, a, 0, 0, 0);
                    a = __builtin_amdgcn_mfma_f32_16x16x32_bf16(am[f], bh, a, 0, 0, 0);
                    a = __builtin_amdgcn_mfma_f32_16x16x32_bf16(ah[f], bl, a, 0, 0, 0);
                    a = __builtin_amdgcn_mfma_f32_16x16x32_bf16(al[f], bh, a, 0, 0, 0);
                    a = __builtin_amdgcn_mfma_f32_16x16x32_bf16(am[f], bm, a, 0, 0, 0);
                    acc[f][g] = a;
                }
            }
        }
    }

    // epilogue: C/D layout col=lane&15 (n), row=(lane>>4)*4+reg (m)
    const int col = lane & 15, quad = lane >> 4;
#pragma unroll
    for (int g = 0; g < 4; g++) {
        int n = nb * 128 + (wn * 4 + g) * 16 + col;
        float bias = cb[n];
#pragma unroll
        for (int f = 0; f < 4; f++) {
            int m0 = mb * 128 + (wm * 4 + f) * 16 + quad * 4;
#pragma unroll
            for (int r = 0; r < 4; r++) {
                int m = m0 + r;
                if (m < HW_)
                    xt[(size_t)m * 512 + n] = fmaxf(acc[f][g][r] + bias, 0.f);
            }
        }
    }
}

// ---------------------------------------------------------------------------
// Kernel 2: 1x1 convs (cls 18ch + bbox 36ch) + softmax fg + anchors + bbox
// transform + clip + min-size filter. One block = 16 positions. (fp32)
// ---------------------------------------------------------------------------
__device__ const float g_bx1[9] = {-84.f,-176.f,-360.f,-56.f,-120.f,-248.f,-36.f,-80.f,-168.f};
__device__ const float g_by1[9] = {-40.f,-88.f,-184.f,-56.f,-120.f,-248.f,-80.f,-168.f,-344.f};
__device__ const float g_bx2[9] = {99.f,191.f,375.f,71.f,135.f,263.f,51.f,95.f,183.f};
__device__ const float g_by2[9] = {55.f,103.f,199.f,71.f,135.f,263.f,95.f,183.f,359.f};

__global__ __launch_bounds__(256) void rpn_head(
    const float* __restrict__ xt,
    const float* __restrict__ cls_w, const float* __restrict__ cls_b,
    const float* __restrict__ bbox_w, const float* __restrict__ bbox_b,
    const float* __restrict__ im_info,
    float* __restrict__ scores, float4* __restrict__ boxes)
{
    __shared__ float xl[16 * 512];
    __shared__ float raw[16][56];
    const int tid = threadIdx.x;
    const int p0 = blockIdx.x * 16;

    {
        const float4* src = (const float4*)(xt + (size_t)p0 * 512);
        float4* dst = (float4*)xl;
        for (int i = tid; i < 2048; i += 256) dst[i] = src[i];
    }
    __syncthreads();

    if (tid < 216) {
        int c  = tid % 54;
        int pg = tid / 54;
        const float* wrow = (c < 18) ? (cls_w + (size_t)c * 512)
                                     : (bbox_w + (size_t)(c - 18) * 512);
        float b = (c < 18) ? cls_b[c] : bbox_b[c - 18];
        float a0 = b, a1 = b, a2 = b, a3 = b;
        const float* x0 = xl + (size_t)(pg * 4) * 512;
        for (int ci = 0; ci < 512; ci++) {
            float wv = wrow[ci];
            a0 = fmaf(wv, x0[ci], a0);
            a1 = fmaf(wv, x0[512 + ci], a1);
            a2 = fmaf(wv, x0[1024 + ci], a2);
            a3 = fmaf(wv, x0[1536 + ci], a3);
        }
        raw[pg * 4 + 0][c] = a0;
        raw[pg * 4 + 1][c] = a1;
        raw[pg * 4 + 2][c] = a2;
        raw[pg * 4 + 3][c] = a3;
    }
    __syncthreads();

    if (tid < 144) {
        int pos = tid / 9;
        int a   = tid % 9;
        int p = p0 + pos;
        int hh = p / 152;
        int ww = p - hh * 152;

        float s0 = raw[pos][a], s1 = raw[pos][9 + a];
        float fg = 1.f / (1.f + expf(s0 - s1));

        float dx = raw[pos][18 + 4 * a + 0];
        float dy = raw[pos][18 + 4 * a + 1];
        float dw = raw[pos][18 + 4 * a + 2];
        float dh = raw[pos][18 + 4 * a + 3];

        float sx = ww * 16.f, sy = hh * 16.f;
        float ax1 = g_bx1[a] + sx, ay1 = g_by1[a] + sy;
        float ax2 = g_bx2[a] + sx, ay2 = g_by2[a] + sy;
        float aw = ax2 - ax1 + 1.f, ah = ay2 - ay1 + 1.f;
        float axc = ax1 + 0.5f * aw, ayc = ay1 + 0.5f * ah;

        float px = dx * aw + axc, py = dy * ah + ayc;
        float pw = expf(dw) * aw, ph = expf(dh) * ah;
        float x1 = px - 0.5f * pw, y1 = py - 0.5f * ph;
        float x2 = px + 0.5f * pw, y2 = py + 0.5f * ph;

        float imh = im_info[0], imw = im_info[1], scl = im_info[2];
        x1 = fminf(fmaxf(x1, 0.f), imw - 1.f);
        y1 = fminf(fmaxf(y1, 0.f), imh - 1.f);
        x2 = fminf(fmaxf(x2, 0.f), imw - 1.f);
        y2 = fminf(fmaxf(y2, 0.f), imh - 1.f);

        float wd = x2 - x1 + 1.f, hd = y2 - y1 + 1.f;
        bool valid = (wd >= 16.f * scl) && (hd >= 16.f * scl);

        int idx = p * 9 + a;
        scores[idx] = valid ? fg : -1000000000.f;
        boxes[idx] = make_float4(x1, y1, x2, y2);
    }
}

// ---------------------------------------------------------------------------
// Top-K: exact bitonic sort (descending) of u64 keys (sortable_score, ~index)
// ---------------------------------------------------------------------------
__global__ void build_keys(const float* __restrict__ scores,
                           unsigned long long* __restrict__ keys)
{
    int i = blockIdx.x * 256 + threadIdx.x;
    if (i >= NSORT_) return;
    unsigned long long k = 0ull;
    if (i < NA_) {
        unsigned u = __float_as_uint(scores[i]);
        u = (u & 0x80000000u) ? ~u : (u | 0x80000000u);
        k = ((unsigned long long)u << 32) | (unsigned)(0xFFFFFFFFu - (unsigned)i);
    }
    keys[i] = k;
}

__device__ __forceinline__ void cex(unsigned long long* s, int i, int l, bool desc)
{
    unsigned long long a = s[i], b = s[l];
    if (desc ? (a < b) : (a > b)) { s[i] = b; s[l] = a; }
}

__global__ __launch_bounds__(256) void bitonic_local_sort(unsigned long long* __restrict__ keys)
{
    __shared__ unsigned long long s[4096];
    const int tid = threadIdx.x;
    const int base = blockIdx.x * 4096;
    for (int i = tid; i < 4096; i += 256) s[i] = keys[base + i];
    __syncthreads();
    for (int k = 2; k <= 4096; k <<= 1) {
        for (int j = k >> 1; j > 0; j >>= 1) {
#pragma unroll
            for (int m = 0; m < 8; m++) {
                int p = tid + m * 256;
                int i = ((p & ~(j - 1)) << 1) | (p & (j - 1));
                int l = i | j;
                bool desc = (((base + i) & k) == 0);
                cex(s, i, l, desc);
            }
            __syncthreads();
        }
    }
    for (int i = tid; i < 4096; i += 256) keys[base + i] = s[i];
}

__global__ void bitonic_global(unsigned long long* __restrict__ keys, int j, int k)
{
    int p = blockIdx.x * 256 + threadIdx.x;
    int i = ((p & ~(j - 1)) << 1) | (p & (j - 1));
    int l = i | j;
    bool desc = ((i & k) == 0);
    unsigned long long a = keys[i], b = keys[l];
    if (desc ? (a < b) : (a > b)) { keys[i] = b; keys[l] = a; }
}

__global__ __launch_bounds__(256) void bitonic_local_merge(unsigned long long* __restrict__ keys, int k)
{
    __shared__ unsigned long long s[4096];
    const int tid = threadIdx.x;
    const int base = blockIdx.x * 4096;
    const bool desc = ((base & k) == 0);
    for (int i = tid; i < 4096; i += 256) s[i] = keys[base + i];
    __syncthreads();
    for (int j = 2048; j > 0; j >>= 1) {
#pragma unroll
        for (int m = 0; m < 8; m++) {
            int p = tid + m * 256;
            int i = ((p & ~(j - 1)) << 1) | (p & (j - 1));
            cex(s, i, i | j, desc);
        }
        __syncthreads();
    }
    for (int i = tid; i < 4096; i += 256) keys[base + i] = s[i];
}

// ---------------------------------------------------------------------------
// Gather top-6000 (padded to 6016) boxes/scores/areas in sorted order
// ---------------------------------------------------------------------------
__global__ void gather_top(const unsigned long long* __restrict__ keys,
                           const float* __restrict__ scores,
                           const float4* __restrict__ boxes,
                           float4* __restrict__ nb, float* __restrict__ sc,
                           float* __restrict__ area)
{
    int r = blockIdx.x * 256 + threadIdx.x;
    if (r >= NB_PAD_) return;
    if (r < PRE_NMS_) {
        unsigned long long key = keys[r];
        unsigned idx = 0xFFFFFFFFu - (unsigned)(key & 0xFFFFFFFFull);
        float4 b = boxes[idx];
        nb[r] = b;
        sc[r] = scores[idx];
        area[r] = (b.z - b.x + 1.f) * (b.w - b.y + 1.f);
    } else {
        nb[r] = make_float4(0.f, 0.f, 0.f, 0.f);
        sc[r] = -1000000000.f;
        area[r] = 1.f;
    }
}

// ---------------------------------------------------------------------------
// NMS suppression bitmatrix + diagonal words
// ---------------------------------------------------------------------------
__global__ __launch_bounds__(64) void nms_mask(const float4* __restrict__ nb,
                                               const float* __restrict__ area,
                                               unsigned long long* __restrict__ mask,
                                               unsigned long long* __restrict__ diag)
{
    __shared__ float4 cbox[64];
    __shared__ float carea[64];
    const int t = threadIdx.x;
    const int cbk = blockIdx.x, rb = blockIdx.y;
    const int jBase = cbk * 64;
    cbox[t] = nb[jBase + t];
    carea[t] = area[jBase + t];
    __syncthreads();

    const int i = rb * 64 + t;
    const float4 bi = nb[i];
    const float ai = area[i];
    unsigned long long bits = 0ull;
#pragma unroll 8
    for (int b = 0; b < 64; b++) {
        int j = jBase + b;
        if (j > i) {
            float4 bj = cbox[b];
            float xx1 = fmaxf(bi.x, bj.x), yy1 = fmaxf(bi.y, bj.y);
            float xx2 = fminf(bi.z, bj.z), yy2 = fminf(bi.w, bj.w);
            float iw = fmaxf(0.f, xx2 - xx1 + 1.f);
            float ih = fmaxf(0.f, yy2 - yy1 + 1.f);
            float inter = iw * ih;
            float iou = inter / (ai + carea[b] - inter);
            if (iou > 0.7f) bits |= (1ull << b);
        }
    }
    mask[(size_t)i * NWORDS_ + cbk] = bits;
    if (cbk == rb) diag[i] = bits;
}

// ---------------------------------------------------------------------------
// Block-serial NMS scan (4 waves, speculative row loads, LDS remv)
// ---------------------------------------------------------------------------
__device__ __forceinline__ unsigned long long readlane_u64(unsigned long long v, int l)
{
    unsigned int lo = (unsigned int)__builtin_amdgcn_readlane((int)(unsigned int)(v & 0xffffffffull), l);
    unsigned int hi = (unsigned int)__builtin_amdgcn_readlane((int)(unsigned int)(v >> 32), l);
    return ((unsigned long long)hi << 32) | (unsigned long long)lo;
}

__global__ __launch_bounds__(256) void nms_scan(const unsigned long long* __restrict__ mask,
                                                const unsigned long long* __restrict__ diag,
                                                int* __restrict__ keep)
{
    __shared__ unsigned long long dlds[NB_PAD_];
    __shared__ unsigned rlo[NWORDS_], rhi[NWORDS_];
    __shared__ unsigned long long aliveSh;
    const int tid = threadIdx.x;
    const int wave = tid >> 6, lane = tid & 63;

    for (int i = tid; i < NB_PAD_; i += 256) dlds[i] = diag[i];
    if (tid < NWORDS_) { rlo[tid] = 0u; rhi[tid] = 0u; }
    __syncthreads();

    for (int c = 0; c < NWORDS_; c++) {
        unsigned long long ext = ((unsigned long long)rhi[c] << 32) | (unsigned long long)rlo[c];
        unsigned long long aliveP = ~ext;

        unsigned long long mysel = aliveP & (0xFFFFull << (wave * 16));
        int rb[16];
        int n = 0;
        while (mysel) { rb[n++] = (int)__builtin_ctzll(mysel); mysel &= mysel - 1; }

        unsigned long long v0[16], v1[16];
#pragma unroll
        for (int i = 0; i < 16; i++) {
            if (i < n) {
                const unsigned long long* row = mask + (size_t)(c * 64 + rb[i]) * NWORDS_;
                v0[i] = row[lane];
                v1[i] = (lane < NWORDS_ - 64) ? row[64 + lane] : 0ull;
            }
        }

        if (wave == 0) {
            unsigned long long myD = dlds[c * 64 + lane];
            unsigned long long alive = aliveP, todo = aliveP;
            while (todo) {
                int l = (int)__builtin_ctzll(todo);
                todo &= todo - 1;
                unsigned long long d = readlane_u64(myD, l);
                alive &= ~d;
                todo &= ~d;
            }
            keep[c * 64 + lane] = (int)((alive >> lane) & 1ull);
            if (lane == 0) aliveSh = alive;
        }
        __syncthreads();

        unsigned long long alive = aliveSh;
        unsigned long long d0 = 0ull, d1 = 0ull;
#pragma unroll
        for (int i = 0; i < 16; i++) {
            if (i < n && ((alive >> rb[i]) & 1ull)) { d0 |= v0[i]; d1 |= v1[i]; }
        }
        if (d0) {
            atomicOr(&rlo[lane], (unsigned)d0);
            atomicOr(&rhi[lane], (unsigned)(d0 >> 32));
        }
        if (lane < NWORDS_ - 64 && d1) {
            atomicOr(&rlo[64 + lane], (unsigned)d1);
            atomicOr(&rhi[64 + lane], (unsigned)(d1 >> 32));
        }
        __syncthreads();
    }
}

// ---------------------------------------------------------------------------
// Final: top-300 of kept (then non-kept in index order to fill) -> rois
// ---------------------------------------------------------------------------
__global__ __launch_bounds__(64) void final_out(const int* __restrict__ keep,
                                                const float* __restrict__ sc,
                                                const float4* __restrict__ nb,
                                                float* __restrict__ out)
{
    __shared__ int sel[POST_NMS_];
    const int lane = threadIdx.x;
    const unsigned long long lmask = (lane == 0) ? 0ull : ((~0ull) >> (64 - lane));

    int cnt = 0;
    for (int c = 0; c < NWORDS_ && cnt < POST_NMS_; c++) {
        int j = c * 64 + lane;
        bool k = (j < PRE_NMS_) && keep[j] && (sc[j] > -5e8f);
        unsigned long long bal = __ballot(k);
        int pos = cnt + __popcll(bal & lmask);
        if (k && pos < POST_NMS_) sel[pos] = j;
        cnt += __popcll(bal);
    }
    if (cnt < POST_NMS_) {
        for (int c = 0; c < NWORDS_ && cnt < POST_NMS_; c++) {
            int j = c * 64 + lane;
            bool k = (j < PRE_NMS_) && !(keep[j] && (sc[j] > -5e8f));
            unsigned long long bal = __ballot(k);
            int pos = cnt + __popcll(bal & lmask);
            if (k && pos < POST_NMS_) sel[pos] = j;
            cnt += __popcll(bal);
        }
    }
    __syncthreads();
    for (int i = lane; i < POST_NMS_; i += 64) {
        int j = sel[i];
        float4 b = nb[j];
        out[i * 5 + 0] = 0.f;
        out[i * 5 + 1] = b.x;
        out[i * 5 + 2] = b.y;
        out[i * 5 + 3] = b.z;
        out[i * 5 + 4] = b.w;
    }
}

// ---------------------------------------------------------------------------
extern "C" void kernel_launch(void* const* d_in, const int* in_sizes, int n_in,
                              void* d_out, int out_size, void* d_ws, size_t ws_size,
                              hipStream_t stream)
{
    const float* fm      = (const float*)d_in[0];
    const float* im_info = (const float*)d_in[1];
    const float* conv_w  = (const float*)d_in[2];
    const float* conv_b  = (const float*)d_in[3];
    const float* cls_w   = (const float*)d_in[4];
    const float* cls_b   = (const float*)d_in[5];
    const float* bbox_w  = (const float*)d_in[6];
    const float* bbox_b  = (const float*)d_in[7];
    float* out = (float*)d_out;

    char* ws = (char*)d_ws;
    size_t off = 0;
    auto alloc = [&](size_t bytes) -> void* {
        void* p = ws + off;
        off = (off + bytes + 255) & ~(size_t)255;
        return p;
    };
    // persistent across phases
    float* xt = (float*)alloc((size_t)HW_ * 512 * 4);   // 31.1 MB

    // phase A (pre/during conv): bf16 split arrays.
    // phase B (post-conv): head outputs + sort + NMS buffers. Aliased.
    size_t phase_base = off;
    __hip_bfloat16* xph = (__hip_bfloat16*)alloc((size_t)NQ_ * 512 * 2);     // 15.3 MiB
    __hip_bfloat16* xpm = (__hip_bfloat16*)alloc((size_t)NQ_ * 512 * 2);
    __hip_bfloat16* xpl = (__hip_bfloat16*)alloc((size_t)NQ_ * 512 * 2);
    __hip_bfloat16* bph = (__hip_bfloat16*)alloc((size_t)9 * 512 * 512 * 2); // 4.5 MiB
    __hip_bfloat16* bpm = (__hip_bfloat16*)alloc((size_t)9 * 512 * 512 * 2);
    __hip_bfloat16* bpl = (__hip_bfloat16*)alloc((size_t)9 * 512 * 512 * 2);

    off = phase_base;  // alias: phase-B buffers reuse phase-A memory
    float* scores             = (float*)alloc((size_t)NA_ * 4);
    float4* boxes             = (float4*)alloc((size_t)NA_ * 16);
    unsigned long long* keys  = (unsigned long long*)alloc((size_t)NSORT_ * 8);
    float4* nb                = (float4*)alloc((size_t)NB_PAD_ * 16);
    float* sc                 = (float*)alloc((size_t)NB_PAD_ * 4);
    float* area               = (float*)alloc((size_t)NB_PAD_ * 4);
    unsigned long long* mask  = (unsigned long long*)alloc((size_t)NB_PAD_ * NWORDS_ * 8);
    unsigned long long* diag  = (unsigned long long*)alloc((size_t)NB_PAD_ * 8);
    int* keep                 = (int*)alloc((size_t)NB_PAD_ * 4);

    pack_x<<<dim3(246, 8), 256, 0, stream>>>(fm, xph, xpm, xpl);
    pack_w<<<dim3(1152), 256, 0, stream>>>(conv_w, bph, bpm, bpl);
    conv_mfma<<<dim3(119, 4), 256, 0, stream>>>(xph, xpm, xpl, bph, bpm, bpl,
                                                conv_b, xt);
    rpn_head<<<dim3(950), 256, 0, stream>>>(xt, cls_w, cls_b, bbox_w, bbox_b,
                                            im_info, scores, boxes);
    build_keys<<<dim3(NSORT_ / 256), 256, 0, stream>>>(scores, keys);
    bitonic_local_sort<<<dim3(NSORT_ / 4096), 256, 0, stream>>>(keys);
    for (int k = 8192; k <= NSORT_; k <<= 1) {
        for (int j = k >> 1; j >= 4096; j >>= 1)
            bitonic_global<<<dim3(NSORT_ / 2 / 256), 256, 0, stream>>>(keys, j, k);
        bitonic_local_merge<<<dim3(NSORT_ / 4096), 256, 0, stream>>>(keys, k);
    }
    gather_top<<<dim3((NB_PAD_ + 255) / 256), 256, 0, stream>>>(keys, scores, boxes,
                                                                nb, sc, area);
    nms_mask<<<dim3(NWORDS_, NWORDS_), 64, 0, stream>>>(nb, area, mask, diag);
    nms_scan<<<dim3(1), 256, 0, stream>>>(mask, diag, keep);
    final_out<<<dim3(1), 64, 0, stream>>>(keep, sc, nb, out);
}

// Round 6
// 1013.398 us; speedup vs baseline: 3.0939x; 1.2593x over previous
//
#include <hip/hip_runtime.h>
#include <hip/hip_bf16.h>
#include <math.h>

#define H_ 100
#define W_ 152
#define HW_ 15200
#define C_ 512
#define A_ 9
#define NA_ 136800        // HW*A
#define NSORT_ 262144     // 2^18 >= NA
#define PRE_NMS_ 6000
#define NB_PAD_ 6016      // PRE_NMS padded to 64
#define NWORDS_ 94        // ceil(6000/64)
#define POST_NMS_ 300

#define QH_ 102           // padded rows
#define QW_ 154           // padded cols
#define NQ_ (QH_ * QW_)   // 15708 padded positions

typedef __attribute__((ext_vector_type(8))) short short8;   // 8 bf16 (4 VGPRs)
typedef __attribute__((ext_vector_type(4))) float f32x4;    // MFMA C/D

#define GLOAD_LDS16(g, l) \
    __builtin_amdgcn_global_load_lds( \
        (const __attribute__((address_space(1))) void*)(g), \
        (__attribute__((address_space(3))) void*)(l), 16, 0, 0)

// ---------------------------------------------------------------------------
// pack_x: fm (fp32 CHW) -> padded HWC bf16 3-term split arrays xp{h,m,l}.
// x = h + m + l (24 mantissa bits, residual ~2^-27). Borders zero.
// ---------------------------------------------------------------------------
__global__ __launch_bounds__(256) void pack_x(const float* __restrict__ fm,
                                              __hip_bfloat16* __restrict__ xph,
                                              __hip_bfloat16* __restrict__ xpm,
                                              __hip_bfloat16* __restrict__ xpl)
{
    __shared__ float t[64][65];
    const int tid = threadIdx.x;
    const int q0 = blockIdx.x * 64;
    const int c0 = blockIdx.y * 64;

    {
        const int qi = tid & 63;
        const int cs = tid >> 6;          // 0..3
        const int q = q0 + qi;
        int hp = q / QW_, wp = q - hp * QW_;
        bool inter = (q < NQ_) && (hp >= 1) && (hp <= 100) && (wp >= 1) && (wp <= 152);
        int p = inter ? ((hp - 1) * W_ + (wp - 1)) : 0;
#pragma unroll
        for (int cc = cs; cc < 64; cc += 4) {
            float v = inter ? fm[(size_t)(c0 + cc) * HW_ + p] : 0.f;
            t[cc][qi] = v;
        }
    }
    __syncthreads();
    {
        const int cl = tid & 63;
        const int qs = tid >> 6;
#pragma unroll
        for (int qq = qs; qq < 64; qq += 4) {
            int qg = q0 + qq;
            if (qg < NQ_) {
                float v = t[cl][qq];
                __hip_bfloat16 h = __float2bfloat16(v);
                float r1 = v - __bfloat162float(h);
                __hip_bfloat16 m = __float2bfloat16(r1);
                float r2 = r1 - __bfloat162float(m);
                __hip_bfloat16 l = __float2bfloat16(r2);
                size_t o = (size_t)qg * 512 + c0 + cl;
                xph[o] = h;
                xpm[o] = m;
                xpl[o] = l;
            }
        }
    }
}

// ---------------------------------------------------------------------------
// pack_w: cw[co][ci][3][3] fp32 -> MFMA B-fragment-ordered bf16 3-term split.
// Layout: [t9][k32][n16][lane(64)][8]
// ---------------------------------------------------------------------------
__global__ __launch_bounds__(256) void pack_w(const float* __restrict__ cw,
                                              __hip_bfloat16* __restrict__ bph,
                                              __hip_bfloat16* __restrict__ bpm,
                                              __hip_bfloat16* __restrict__ bpl)
{
    int id = blockIdx.x * 256 + threadIdx.x;      // 294912 total
    int lane = id & 63;
    int rest = id >> 6;
    int n16 = rest & 31;
    int tk = rest >> 5;
    int k32 = tk & 15;
    int t9 = tk >> 4;
    if (t9 >= 9) return;
    int ky = t9 / 3, kx = t9 - ky * 3;
    int n = n16 * 16 + (lane & 15);
    int kb = k32 * 32 + (lane >> 4) * 8;

    union H8 { short8 s; __hip_bfloat16 b[8]; } hv, mv, lv;
#pragma unroll
    for (int j = 0; j < 8; j++) {
        int ci = kb + j;
        float v = cw[(((size_t)n * 512 + ci) * 3 + ky) * 3 + kx];
        __hip_bfloat16 h = __float2bfloat16(v);
        float r1 = v - __bfloat162float(h);
        __hip_bfloat16 m = __float2bfloat16(r1);
        float r2 = r1 - __bfloat162float(m);
        hv.b[j] = h;
        mv.b[j] = m;
        lv.b[j] = __float2bfloat16(r2);
    }
    *(short8*)((short*)bph + (size_t)id * 8) = hv.s;
    *(short8*)((short*)bpm + (size_t)id * 8) = mv.s;
    *(short8*)((short*)bpl + (size_t)id * 8) = lv.s;
}

// ---------------------------------------------------------------------------
// conv_mfma: 3x3 conv as 9-tap implicit GEMM, bf16 3-term split, fp32 acc.
// v3: m97-style staging — global_load_lds width=16 (direct global->LDS DMA,
// no VGPR round-trip), flattened 144-iter loop, 2 barriers/iter.
// Block = 128m x 128n, 4 waves 2x2, wave = 64m x 64n (4x4 frags).
// LDS: A 24 slots + B 24 slots, each [64][8] shorts (lane-major 16B).
// ---------------------------------------------------------------------------
__global__ __launch_bounds__(256, 2) void conv_mfma(
    const __hip_bfloat16* __restrict__ xph, const __hip_bfloat16* __restrict__ xpm,
    const __hip_bfloat16* __restrict__ xpl,
    const __hip_bfloat16* __restrict__ bph, const __hip_bfloat16* __restrict__ bpm,
    const __hip_bfloat16* __restrict__ bpl,
    const float* __restrict__ cb, float* __restrict__ xt)
{
    __shared__ short a_lds[24][64][8];   // 24 KB, slot = mf*3 + arr
    __shared__ short b_lds[24][64][8];   // 24 KB, slot = nf*3 + arr

    const int tid = threadIdx.x;
    const int wave = tid >> 6, lane = tid & 63;
    const int wm = wave >> 1, wn = wave & 1;
    const int mb = blockIdx.x, nb = blockIdx.y;

    const __hip_bfloat16* xarr[3] = {xph, xpm, xpl};
    const __hip_bfloat16* barr[3] = {bph, bpm, bpl};

    // staging: wave w owns slots w*6 .. w*6+5 (A and B)
    const int sBase = wave * 6;
    const short* aSrc[6];
    const short* bSrc[6];
#pragma unroll
    for (int i = 0; i < 6; i++) {
        int s = sBase + i;                // 0..23
        int f = s / 3, arr = s - 3 * (s / 3);
        int m = mb * 128 + f * 16 + (lane & 15);
        int hh = m / W_, ww = m - hh * W_;
        int q = (hh + 1) * QW_ + (ww + 1);
        aSrc[i] = (const short*)xarr[arr] + (size_t)q * 512 + (lane >> 4) * 8;
        bSrc[i] = (const short*)barr[arr] + (size_t)(nb * 8 + f) * 512 + lane * 8;
    }

    f32x4 acc[4][4];
#pragma unroll
    for (int f = 0; f < 4; f++)
#pragma unroll
        for (int g = 0; g < 4; g++)
            acc[f][g] = (f32x4){0.f, 0.f, 0.f, 0.f};

    for (int it = 0; it < 144; it++) {
        const int t9 = it >> 4;           // 144 = 9*16
        const int k32 = it & 15;
        const int t3 = t9 / 3;
        const int dy = t3 - 1, dx = t9 - t3 * 3 - 1;
        const int offA = ((dy * QW_ + dx) << 9) + (k32 << 5);  // shorts
        const int offB = it << 14;                              // shorts

        __syncthreads();
#pragma unroll
        for (int i = 0; i < 6; i++) {
            GLOAD_LDS16(aSrc[i] + offA, &a_lds[sBase + i][0][0]);
            GLOAD_LDS16(bSrc[i] + offB, &b_lds[sBase + i][0][0]);
        }
        __syncthreads();

        short8 ah[4], am[4], al[4];
#pragma unroll
        for (int f = 0; f < 4; f++) {
            ah[f] = *(const short8*)&a_lds[(wm * 4 + f) * 3 + 0][lane][0];
            am[f] = *(const short8*)&a_lds[(wm * 4 + f) * 3 + 1][lane][0];
            al[f] = *(const short8*)&a_lds[(wm * 4 + f) * 3 + 2][lane][0];
        }
#pragma unroll
        for (int g = 0; g < 4; g++) {
            short8 bh = *(const short8*)&b_lds[(wn * 4 + g) * 3 + 0][lane][0];
            short8 bm = *(const short8*)&b_lds[(wn * 4 + g) * 3 + 1][lane][0];
            short8 bl = *(const short8*)&b_lds[(wn * 4 + g) * 3 + 2][lane][0];
#pragma unroll
            for (int f = 0; f < 4; f++) {
                f32x4 a = acc[f][g];
                a = __builtin_amdgcn_mfma_f32_16x16x32_bf16(ah[f], bh, a, 0, 0, 0);
                a = __builtin_amdgcn_mfma_f32_16x16x32_bf16(ah[f], bm, a, 0, 0, 0);
                a = __builtin_amdgcn_mfma_f32_16x16x32_bf16(am[f], bh, a, 0, 0, 0);
                a = __builtin_amdgcn_mfma_f32_16x16x32_bf16(ah[f], bl, a, 0, 0, 0);
                a = __builtin_amdgcn_mfma_f32_16x16x32_bf16(al[f], bh, a, 0, 0, 0);
                a = __builtin_amdgcn_mfma_f32_16x16x32_bf16(am[f], bm, a, 0, 0, 0);
                acc[f][g] = a;
            }
        }
    }

    // epilogue: C/D layout col=lane&15 (n), row=(lane>>4)*4+reg (m)
    const int col = lane & 15, quad = lane >> 4;
#pragma unroll
    for (int g = 0; g < 4; g++) {
        int n = nb * 128 + (wn * 4 + g) * 16 + col;
        float bias = cb[n];
#pragma unroll
        for (int f = 0; f < 4; f++) {
            int m0 = mb * 128 + (wm * 4 + f) * 16 + quad * 4;
#pragma unroll
            for (int r = 0; r < 4; r++) {
                int m = m0 + r;
                if (m < HW_)
                    xt[(size_t)m * 512 + n] = fmaxf(acc[f][g][r] + bias, 0.f);
            }
        }
    }
}

// ---------------------------------------------------------------------------
// Kernel 2: 1x1 convs (cls 18ch + bbox 36ch) + softmax fg + anchors + bbox
// transform + clip + min-size filter. One block = 16 positions. (fp32)
// ---------------------------------------------------------------------------
__device__ const float g_bx1[9] = {-84.f,-176.f,-360.f,-56.f,-120.f,-248.f,-36.f,-80.f,-168.f};
__device__ const float g_by1[9] = {-40.f,-88.f,-184.f,-56.f,-120.f,-248.f,-80.f,-168.f,-344.f};
__device__ const float g_bx2[9] = {99.f,191.f,375.f,71.f,135.f,263.f,51.f,95.f,183.f};
__device__ const float g_by2[9] = {55.f,103.f,199.f,71.f,135.f,263.f,95.f,183.f,359.f};

__global__ __launch_bounds__(256) void rpn_head(
    const float* __restrict__ xt,
    const float* __restrict__ cls_w, const float* __restrict__ cls_b,
    const float* __restrict__ bbox_w, const float* __restrict__ bbox_b,
    const float* __restrict__ im_info,
    float* __restrict__ scores, float4* __restrict__ boxes)
{
    __shared__ float xl[16 * 512];
    __shared__ float raw[16][56];
    const int tid = threadIdx.x;
    const int p0 = blockIdx.x * 16;

    {
        const float4* src = (const float4*)(xt + (size_t)p0 * 512);
        float4* dst = (float4*)xl;
        for (int i = tid; i < 2048; i += 256) dst[i] = src[i];
    }
    __syncthreads();

    if (tid < 216) {
        int c  = tid % 54;
        int pg = tid / 54;
        const float* wrow = (c < 18) ? (cls_w + (size_t)c * 512)
                                     : (bbox_w + (size_t)(c - 18) * 512);
        float b = (c < 18) ? cls_b[c] : bbox_b[c - 18];
        float a0 = b, a1 = b, a2 = b, a3 = b;
        const float* x0 = xl + (size_t)(pg * 4) * 512;
        for (int ci = 0; ci < 512; ci++) {
            float wv = wrow[ci];
            a0 = fmaf(wv, x0[ci], a0);
            a1 = fmaf(wv, x0[512 + ci], a1);
            a2 = fmaf(wv, x0[1024 + ci], a2);
            a3 = fmaf(wv, x0[1536 + ci], a3);
        }
        raw[pg * 4 + 0][c] = a0;
        raw[pg * 4 + 1][c] = a1;
        raw[pg * 4 + 2][c] = a2;
        raw[pg * 4 + 3][c] = a3;
    }
    __syncthreads();

    if (tid < 144) {
        int pos = tid / 9;
        int a   = tid % 9;
        int p = p0 + pos;
        int hh = p / 152;
        int ww = p - hh * 152;

        float s0 = raw[pos][a], s1 = raw[pos][9 + a];
        float fg = 1.f / (1.f + expf(s0 - s1));

        float dx = raw[pos][18 + 4 * a + 0];
        float dy = raw[pos][18 + 4 * a + 1];
        float dw = raw[pos][18 + 4 * a + 2];
        float dh = raw[pos][18 + 4 * a + 3];

        float sx = ww * 16.f, sy = hh * 16.f;
        float ax1 = g_bx1[a] + sx, ay1 = g_by1[a] + sy;
        float ax2 = g_bx2[a] + sx, ay2 = g_by2[a] + sy;
        float aw = ax2 - ax1 + 1.f, ah = ay2 - ay1 + 1.f;
        float axc = ax1 + 0.5f * aw, ayc = ay1 + 0.5f * ah;

        float px = dx * aw + axc, py = dy * ah + ayc;
        float pw = expf(dw) * aw, ph = expf(dh) * ah;
        float x1 = px - 0.5f * pw, y1 = py - 0.5f * ph;
        float x2 = px + 0.5f * pw, y2 = py + 0.5f * ph;

        float imh = im_info[0], imw = im_info[1], scl = im_info[2];
        x1 = fminf(fmaxf(x1, 0.f), imw - 1.f);
        y1 = fminf(fmaxf(y1, 0.f), imh - 1.f);
        x2 = fminf(fmaxf(x2, 0.f), imw - 1.f);
        y2 = fminf(fmaxf(y2, 0.f), imh - 1.f);

        float wd = x2 - x1 + 1.f, hd = y2 - y1 + 1.f;
        bool valid = (wd >= 16.f * scl) && (hd >= 16.f * scl);

        int idx = p * 9 + a;
        scores[idx] = valid ? fg : -1000000000.f;
        boxes[idx] = make_float4(x1, y1, x2, y2);
    }
}

// ---------------------------------------------------------------------------
// Top-K: exact bitonic sort (descending) of u64 keys (sortable_score, ~index).
// Key-build fused into the local sort's load phase.
// ---------------------------------------------------------------------------
__device__ __forceinline__ void cex(unsigned long long* s, int i, int l, bool desc)
{
    unsigned long long a = s[i], b = s[l];
    if (desc ? (a < b) : (a > b)) { s[i] = b; s[l] = a; }
}

__global__ __launch_bounds__(256) void bitonic_local_sort(const float* __restrict__ scores,
                                                          unsigned long long* __restrict__ keys)
{
    __shared__ unsigned long long s[4096];
    const int tid = threadIdx.x;
    const int base = blockIdx.x * 4096;
    for (int i = tid; i < 4096; i += 256) {
        int g = base + i;
        unsigned long long k = 0ull;
        if (g < NA_) {
            unsigned u = __float_as_uint(scores[g]);
            u = (u & 0x80000000u) ? ~u : (u | 0x80000000u);
            k = ((unsigned long long)u << 32) | (unsigned)(0xFFFFFFFFu - (unsigned)g);
        }
        s[i] = k;
    }
    __syncthreads();
    for (int k = 2; k <= 4096; k <<= 1) {
        for (int j = k >> 1; j > 0; j >>= 1) {
#pragma unroll
            for (int m = 0; m < 8; m++) {
                int p = tid + m * 256;
                int i = ((p & ~(j - 1)) << 1) | (p & (j - 1));
                int l = i | j;
                bool desc = (((base + i) & k) == 0);
                cex(s, i, l, desc);
            }
            __syncthreads();
        }
    }
    for (int i = tid; i < 4096; i += 256) keys[base + i] = s[i];
}

__global__ void bitonic_global(unsigned long long* __restrict__ keys, int j, int k)
{
    int p = blockIdx.x * 256 + threadIdx.x;
    int i = ((p & ~(j - 1)) << 1) | (p & (j - 1));
    int l = i | j;
    bool desc = ((i & k) == 0);
    unsigned long long a = keys[i], b = keys[l];
    if (desc ? (a < b) : (a > b)) { keys[i] = b; keys[l] = a; }
}

__global__ __launch_bounds__(256) void bitonic_local_merge(unsigned long long* __restrict__ keys, int k)
{
    __shared__ unsigned long long s[4096];
    const int tid = threadIdx.x;
    const int base = blockIdx.x * 4096;
    const bool desc = ((base & k) == 0);
    for (int i = tid; i < 4096; i += 256) s[i] = keys[base + i];
    __syncthreads();
    for (int j = 2048; j > 0; j >>= 1) {
#pragma unroll
        for (int m = 0; m < 8; m++) {
            int p = tid + m * 256;
            int i = ((p & ~(j - 1)) << 1) | (p & (j - 1));
            cex(s, i, i | j, desc);
        }
        __syncthreads();
    }
    for (int i = tid; i < 4096; i += 256) keys[base + i] = s[i];
}

// ---------------------------------------------------------------------------
// Gather top-6000 (padded to 6016) boxes/scores/areas in sorted order
// ---------------------------------------------------------------------------
__global__ void gather_top(const unsigned long long* __restrict__ keys,
                           const float* __restrict__ scores,
                           const float4* __restrict__ boxes,
                           float4* __restrict__ nb, float* __restrict__ sc,
                           float* __restrict__ area)
{
    int r = blockIdx.x * 256 + threadIdx.x;
    if (r >= NB_PAD_) return;
    if (r < PRE_NMS_) {
        unsigned long long key = keys[r];
        unsigned idx = 0xFFFFFFFFu - (unsigned)(key & 0xFFFFFFFFull);
        float4 b = boxes[idx];
        nb[r] = b;
        sc[r] = scores[idx];
        area[r] = (b.z - b.x + 1.f) * (b.w - b.y + 1.f);
    } else {
        nb[r] = make_float4(0.f, 0.f, 0.f, 0.f);
        sc[r] = -1000000000.f;
        area[r] = 1.f;
    }
}

// ---------------------------------------------------------------------------
// NMS suppression bitmatrix + diagonal words
// ---------------------------------------------------------------------------
__global__ __launch_bounds__(64) void nms_mask(const float4* __restrict__ nb,
                                               const float* __restrict__ area,
                                               unsigned long long* __restrict__ mask,
                                               unsigned long long* __restrict__ diag)
{
    __shared__ float4 cbox[64];
    __shared__ float carea[64];
    const int t = threadIdx.x;
    const int cbk = blockIdx.x, rb = blockIdx.y;
    const int jBase = cbk * 64;
    cbox[t] = nb[jBase + t];
    carea[t] = area[jBase + t];
    __syncthreads();

    const int i = rb * 64 + t;
    const float4 bi = nb[i];
    const float ai = area[i];
    unsigned long long bits = 0ull;
#pragma unroll 8
    for (int b = 0; b < 64; b++) {
        int j = jBase + b;
        if (j > i) {
            float4 bj = cbox[b];
            float xx1 = fmaxf(bi.x, bj.x), yy1 = fmaxf(bi.y, bj.y);
            float xx2 = fminf(bi.z, bj.z), yy2 = fminf(bi.w, bj.w);
            float iw = fmaxf(0.f, xx2 - xx1 + 1.f);
            float ih = fmaxf(0.f, yy2 - yy1 + 1.f);
            float inter = iw * ih;
            float iou = inter / (ai + carea[b] - inter);
            if (iou > 0.7f) bits |= (1ull << b);
        }
    }
    mask[(size_t)i * NWORDS_ + cbk] = bits;
    if (cbk == rb) diag[i] = bits;
}

// ---------------------------------------------------------------------------
// Block-serial NMS scan (4 waves, speculative row loads, LDS remv)
// ---------------------------------------------------------------------------
__device__ __forceinline__ unsigned long long readlane_u64(unsigned long long v, int l)
{
    unsigned int lo = (unsigned int)__builtin_amdgcn_readlane((int)(unsigned int)(v & 0xffffffffull), l);
    unsigned int hi = (unsigned int)__builtin_amdgcn_readlane((int)(unsigned int)(v >> 32), l);
    return ((unsigned long long)hi << 32) | (unsigned long long)lo;
}

__global__ __launch_bounds__(256) void nms_scan(const unsigned long long* __restrict__ mask,
                                                const unsigned long long* __restrict__ diag,
                                                int* __restrict__ keep)
{
    __shared__ unsigned long long dlds[NB_PAD_];
    __shared__ unsigned rlo[NWORDS_], rhi[NWORDS_];
    __shared__ unsigned long long aliveSh;
    const int tid = threadIdx.x;
    const int wave = tid >> 6, lane = tid & 63;

    for (int i = tid; i < NB_PAD_; i += 256) dlds[i] = diag[i];
    if (tid < NWORDS_) { rlo[tid] = 0u; rhi[tid] = 0u; }
    __syncthreads();

    for (int c = 0; c < NWORDS_; c++) {
        unsigned long long ext = ((unsigned long long)rhi[c] << 32) | (unsigned long long)rlo[c];
        unsigned long long aliveP = ~ext;

        unsigned long long mysel = aliveP & (0xFFFFull << (wave * 16));
        int rb[16];
        int n = 0;
        while (mysel) { rb[n++] = (int)__builtin_ctzll(mysel); mysel &= mysel - 1; }

        unsigned long long v0[16], v1[16];
#pragma unroll
        for (int i = 0; i < 16; i++) {
            if (i < n) {
                const unsigned long long* row = mask + (size_t)(c * 64 + rb[i]) * NWORDS_;
                v0[i] = row[lane];
                v1[i] = (lane < NWORDS_ - 64) ? row[64 + lane] : 0ull;
            }
        }

        if (wave == 0) {
            unsigned long long myD = dlds[c * 64 + lane];
            unsigned long long alive = aliveP, todo = aliveP;
            while (todo) {
                int l = (int)__builtin_ctzll(todo);
                todo &= todo - 1;
                unsigned long long d = readlane_u64(myD, l);
                alive &= ~d;
                todo &= ~d;
            }
            keep[c * 64 + lane] = (int)((alive >> lane) & 1ull);
            if (lane == 0) aliveSh = alive;
        }
        __syncthreads();

        unsigned long long alive = aliveSh;
        unsigned long long d0 = 0ull, d1 = 0ull;
#pragma unroll
        for (int i = 0; i < 16; i++) {
            if (i < n && ((alive >> rb[i]) & 1ull)) { d0 |= v0[i]; d1 |= v1[i]; }
        }
        if (d0) {
            atomicOr(&rlo[lane], (unsigned)d0);
            atomicOr(&rhi[lane], (unsigned)(d0 >> 32));
        }
        if (lane < NWORDS_ - 64 && d1) {
            atomicOr(&rlo[64 + lane], (unsigned)d1);
            atomicOr(&rhi[64 + lane], (unsigned)(d1 >> 32));
        }
        __syncthreads();
    }
}

// ---------------------------------------------------------------------------
// Final: top-300 of kept (then non-kept in index order to fill) -> rois
// ---------------------------------------------------------------------------
__global__ __launch_bounds__(64) void final_out(const int* __restrict__ keep,
                                                const float* __restrict__ sc,
                                                const float4* __restrict__ nb,
                                                float* __restrict__ out)
{
    __shared__ int sel[POST_NMS_];
    const int lane = threadIdx.x;
    const unsigned long long lmask = (lane == 0) ? 0ull : ((~0ull) >> (64 - lane));

    int cnt = 0;
    for (int c = 0; c < NWORDS_ && cnt < POST_NMS_; c++) {
        int j = c * 64 + lane;
        bool k = (j < PRE_NMS_) && keep[j] && (sc[j] > -5e8f);
        unsigned long long bal = __ballot(k);
        int pos = cnt + __popcll(bal & lmask);
        if (k && pos < POST_NMS_) sel[pos] = j;
        cnt += __popcll(bal);
    }
    if (cnt < POST_NMS_) {
        for (int c = 0; c < NWORDS_ && cnt < POST_NMS_; c++) {
            int j = c * 64 + lane;
            bool k = (j < PRE_NMS_) && !(keep[j] && (sc[j] > -5e8f));
            unsigned long long bal = __ballot(k);
            int pos = cnt + __popcll(bal & lmask);
            if (k && pos < POST_NMS_) sel[pos] = j;
            cnt += __popcll(bal);
        }
    }
    __syncthreads();
    for (int i = lane; i < POST_NMS_; i += 64) {
        int j = sel[i];
        float4 b = nb[j];
        out[i * 5 + 0] = 0.f;
        out[i * 5 + 1] = b.x;
        out[i * 5 + 2] = b.y;
        out[i * 5 + 3] = b.z;
        out[i * 5 + 4] = b.w;
    }
}

// ---------------------------------------------------------------------------
extern "C" void kernel_launch(void* const* d_in, const int* in_sizes, int n_in,
                              void* d_out, int out_size, void* d_ws, size_t ws_size,
                              hipStream_t stream)
{
    const float* fm      = (const float*)d_in[0];
    const float* im_info = (const float*)d_in[1];
    const float* conv_w  = (const float*)d_in[2];
    const float* conv_b  = (const float*)d_in[3];
    const float* cls_w   = (const float*)d_in[4];
    const float* cls_b   = (const float*)d_in[5];
    const float* bbox_w  = (const float*)d_in[6];
    const float* bbox_b  = (const float*)d_in[7];
    float* out = (float*)d_out;

    char* ws = (char*)d_ws;
    size_t off = 0;
    auto alloc = [&](size_t bytes) -> void* {
        void* p = ws + off;
        off = (off + bytes + 255) & ~(size_t)255;
        return p;
    };
    // persistent across phases
    float* xt = (float*)alloc((size_t)HW_ * 512 * 4);   // 31.1 MB

    // phase A (pre/during conv): bf16 split arrays.
    // phase B (post-conv): head outputs + sort + NMS buffers. Aliased.
    size_t phase_base = off;
    __hip_bfloat16* xph = (__hip_bfloat16*)alloc((size_t)NQ_ * 512 * 2);     // 15.3 MiB
    __hip_bfloat16* xpm = (__hip_bfloat16*)alloc((size_t)NQ_ * 512 * 2);
    __hip_bfloat16* xpl = (__hip_bfloat16*)alloc((size_t)NQ_ * 512 * 2);
    __hip_bfloat16* bph = (__hip_bfloat16*)alloc((size_t)9 * 512 * 512 * 2); // 4.5 MiB
    __hip_bfloat16* bpm = (__hip_bfloat16*)alloc((size_t)9 * 512 * 512 * 2);
    __hip_bfloat16* bpl = (__hip_bfloat16*)alloc((size_t)9 * 512 * 512 * 2);

    off = phase_base;  // alias: phase-B buffers reuse phase-A memory
    float* scores             = (float*)alloc((size_t)NA_ * 4);
    float4* boxes             = (float4*)alloc((size_t)NA_ * 16);
    unsigned long long* keys  = (unsigned long long*)alloc((size_t)NSORT_ * 8);
    float4* nb                = (float4*)alloc((size_t)NB_PAD_ * 16);
    float* sc                 = (float*)alloc((size_t)NB_PAD_ * 4);
    float* area               = (float*)alloc((size_t)NB_PAD_ * 4);
    unsigned long long* mask  = (unsigned long long*)alloc((size_t)NB_PAD_ * NWORDS_ * 8);
    unsigned long long* diag  = (unsigned long long*)alloc((size_t)NB_PAD_ * 8);
    int* keep                 = (int*)alloc((size_t)NB_PAD_ * 4);

    pack_x<<<dim3(246, 8), 256, 0, stream>>>(fm, xph, xpm, xpl);
    pack_w<<<dim3(1152), 256, 0, stream>>>(conv_w, bph, bpm, bpl);
    conv_mfma<<<dim3(119, 4), 256, 0, stream>>>(xph, xpm, xpl, bph, bpm, bpl,
                                                conv_b, xt);
    rpn_head<<<dim3(950), 256, 0, stream>>>(xt, cls_w, cls_b, bbox_w, bbox_b,
                                            im_info, scores, boxes);
    bitonic_local_sort<<<dim3(NSORT_ / 4096), 256, 0, stream>>>(scores, keys);
    for (int k = 8192; k <= NSORT_; k <<= 1) {
        for (int j = k >> 1; j >= 4096; j >>= 1)
            bitonic_global<<<dim3(NSORT_ / 2 / 256), 256, 0, stream>>>(keys, j, k);
        bitonic_local_merge<<<dim3(NSORT_ / 4096), 256, 0, stream>>>(keys, k);
    }
    gather_top<<<dim3((NB_PAD_ + 255) / 256), 256, 0, stream>>>(keys, scores, boxes,
                                                                nb, sc, area);
    nms_mask<<<dim3(NWORDS_, NWORDS_), 64, 0, stream>>>(nb, area, mask, diag);
    nms_scan<<<dim3(1), 256, 0, stream>>>(mask, diag, keep);
    final_out<<<dim3(1), 64, 0, stream>>>(keep, sc, nb, out);
}